// Round 8
// baseline (313.665 us; speedup 1.0000x reference)
//
#include <hip/hip_runtime.h>
#include <math.h>

// ALiBi attention: B=2, T=2048, D=1024, H=16, hd=64. fp32 in/out.
// Round 15: LDS bank-conflict pad fix in flash. sVt2 stride 34->35 words
// (V-transpose writes were a 16-way conflict: banks {0,8,16,24} only --
// matches the measured 5.95M SQ_LDS_BANK_CONFLICT), sP stride 72->74 shorts
// (writes ~4-way -> ~2-way). Pure padding; all logic identical to round 14.

#define T_SEQ 2048
#define DM    1024
#define NH    16
#define HD    64
#define NROW  4096   // B*T
#define NCHB  80     // chunks per (h,b): qt/8 -> 1,2,3,4 chunks

typedef __attribute__((ext_vector_type(8))) short bf16x8;
typedef __attribute__((ext_vector_type(4))) short bf16x4;
typedef __attribute__((ext_vector_type(4))) float f32x4;

template <bool M> struct BoolT { static constexpr bool value = M; };

__device__ __forceinline__ short f2bf(float f) {
  unsigned u = __float_as_uint(f);
  u += 0x7FFFu + ((u >> 16) & 1u);
  return (short)(u >> 16);
}
__device__ __forceinline__ float bf2f(short s) {
  return __uint_as_float(((unsigned)(unsigned short)s) << 16);
}

// RNE pack of two f32 -> {lo16=bf16(a), hi16=bf16(b)} in one instruction.
__device__ __forceinline__ unsigned cvt_pk_bf16(float a, float b) {
  unsigned r;
  asm("v_cvt_pk_bf16_f32 %0, %1, %2" : "=v"(r) : "v"(a), "v"(b));
  return r;
}

#if __has_builtin(__builtin_amdgcn_exp2f)
#define EXP2F(x) __builtin_amdgcn_exp2f(x)
#else
#define EXP2F(x) exp2f(x)
#endif

// async global->LDS, 16B per lane; lds dest is wave-uniform base + lane*16B.
__device__ __forceinline__ void gload_lds16(short* lds, const short* g) {
  __builtin_amdgcn_global_load_lds((const __attribute__((address_space(1))) void*)g,
                                   (__attribute__((address_space(3))) void*)lds, 16, 0, 0);
}

// ---------------------------------------------------------------------------
// Merged fp32->bf16 conversion: x (4M) + 4 weights (1M each), 2M float4 groups.
// ---------------------------------------------------------------------------
__global__ __launch_bounds__(256) void convert_all(
    const float* __restrict__ x,  const float* __restrict__ wq,
    const float* __restrict__ wk, const float* __restrict__ wv,
    const float* __restrict__ wo,
    short* __restrict__ xb,  short* __restrict__ wqb, short* __restrict__ wkb,
    short* __restrict__ wvb, short* __restrict__ wob) {
  const int i = blockIdx.x * 256 + threadIdx.x;
  const float* s; short* d; int off;
  if (i < (1 << 20)) { s = x; d = xb; off = i; }
  else {
    const int j = i - (1 << 20);
    const int w = j >> 18;
    off = j & ((1 << 18) - 1);
    s = (w == 0) ? wq : (w == 1) ? wk : (w == 2) ? wv : wo;
    d = (w == 0) ? wqb : (w == 1) ? wkb : (w == 2) ? wvb : wob;
  }
  const float4 v = ((const float4*)s)[off];
  bf16x4 o = {f2bf(v.x), f2bf(v.y), f2bf(v.z), f2bf(v.w)};
  *(bf16x4*)(d + 4 * (size_t)off) = o;
}

// ---------------------------------------------------------------------------
// GEMM (round-5 exact): C[m][n] = sum_k A[m][k]*W[n][k]. 128x128, BK=32.
// ---------------------------------------------------------------------------
template <typename OutT>
__device__ __forceinline__ void gemm_body(const short* __restrict__ A,
                                          const short* __restrict__ W,
                                          OutT* __restrict__ C) {
  __shared__ short sA[128][32];
  __shared__ short sB[128][32];
  const int tid  = threadIdx.x;
  const int lane = tid & 63, wv = tid >> 6;
  const int quad = lane >> 4, l16 = lane & 15;
  const int wm = (wv >> 1) * 64, wn = (wv & 1) * 64;
  const size_t m0 = (size_t)blockIdx.x * 128, n0 = (size_t)blockIdx.y * 128;

  f32x4 acc[4][4];
#pragma unroll
  for (int i = 0; i < 4; ++i)
#pragma unroll
    for (int j = 0; j < 4; ++j) acc[i][j] = (f32x4){0.f, 0.f, 0.f, 0.f};

  const int grow = lane >> 2;
  const int gcol = (lane & 3) << 3;

  for (int k0 = 0; k0 < DM; k0 += 32) {
    __syncthreads();
    {
      const short* ga = A + (m0 + wv * 32 + grow) * DM + k0 + gcol;
      gload_lds16(&sA[wv * 32][0],      ga);
      gload_lds16(&sA[wv * 32 + 16][0], ga + 16 * DM);
      const short* gb = W + (n0 + wv * 32 + grow) * DM + k0 + gcol;
      gload_lds16(&sB[wv * 32][0],      gb);
      gload_lds16(&sB[wv * 32 + 16][0], gb + 16 * DM);
    }
    __syncthreads();

    bf16x8 af[4], bfr[4];
#pragma unroll
    for (int t = 0; t < 4; ++t) {
      af[t]  = *(const bf16x8*)&sA[wm + t * 16 + l16][quad * 8];
      bfr[t] = *(const bf16x8*)&sB[wn + t * 16 + l16][quad * 8];
    }
#pragma unroll
    for (int mt = 0; mt < 4; ++mt)
#pragma unroll
      for (int nt = 0; nt < 4; ++nt)
        acc[mt][nt] = __builtin_amdgcn_mfma_f32_16x16x32_bf16(af[mt], bfr[nt], acc[mt][nt], 0, 0, 0);
  }
#pragma unroll
  for (int mt = 0; mt < 4; ++mt) {
#pragma unroll
    for (int r = 0; r < 4; ++r) {
      const size_t m = m0 + wm + mt * 16 + quad * 4 + r;
      OutT* crow = C + m * DM;
#pragma unroll
      for (int nt = 0; nt < 4; ++nt) {
        const float v = acc[mt][nt][r];
        if constexpr (sizeof(OutT) == 2)
          crow[n0 + wn + nt * 16 + l16] = f2bf(v);
        else
          crow[n0 + wn + nt * 16 + l16] = v;
      }
    }
  }
}

__global__ __launch_bounds__(256) void gemm_qkv(
    const short* __restrict__ x,
    const short* __restrict__ Wq, const short* __restrict__ Wk, const short* __restrict__ Wv,
    short* __restrict__ Qb, short* __restrict__ Kb, short* __restrict__ Vb) {
  const short* W = (blockIdx.z == 0) ? Wq : (blockIdx.z == 1) ? Wk : Wv;
  short*       C = (blockIdx.z == 0) ? Qb : (blockIdx.z == 1) ? Kb : Vb;
  gemm_body<short>(x, W, C);
}

// ---------------------------------------------------------------------------
// Output GEMM: 64x128 tile (grid 64x8 = 512 blocks = 2/CU). Same 2-barrier
// gload_lds staging pattern; 4 waves as 2x2, each wave 32x64 (acc[2][4]).
// Staging: 12 chunks of 16 rows ([A:4][B:8]), 3 chunks per wave.
// ---------------------------------------------------------------------------
__global__ __launch_bounds__(256) void gemm_out(const short* __restrict__ A,
                                                const short* __restrict__ W,
                                                float* __restrict__ C) {
  __shared__ short sA[64][32];
  __shared__ short sB[128][32];
  const int tid  = threadIdx.x;
  const int lane = tid & 63, wv = tid >> 6;
  const int quad = lane >> 4, l16 = lane & 15;
  const int wm = (wv >> 1) * 32, wn = (wv & 1) * 64;
  const size_t m0 = (size_t)blockIdx.x * 64, n0 = (size_t)blockIdx.y * 128;

  f32x4 acc[2][4];
#pragma unroll
  for (int i = 0; i < 2; ++i)
#pragma unroll
    for (int j = 0; j < 4; ++j) acc[i][j] = (f32x4){0.f, 0.f, 0.f, 0.f};

  const int grow = lane >> 2;
  const int gcol = (lane & 3) << 3;

  for (int k0 = 0; k0 < DM; k0 += 32) {
    __syncthreads();
#pragma unroll
    for (int cc = 0; cc < 3; ++cc) {
      const int i = wv * 3 + cc;   // 0..11, wave-uniform per call
      short* dst = (i < 4) ? &sA[i * 16][0] : &sB[(i - 4) * 16][0];
      const short* src = (i < 4)
          ? A + (m0 + i * 16 + grow) * DM + k0 + gcol
          : W + (n0 + (i - 4) * 16 + grow) * DM + k0 + gcol;
      gload_lds16(dst, src);
    }
    __syncthreads();

    bf16x8 af[2], bfr[4];
#pragma unroll
    for (int t = 0; t < 2; ++t)
      af[t] = *(const bf16x8*)&sA[wm + t * 16 + l16][quad * 8];
#pragma unroll
    for (int t = 0; t < 4; ++t)
      bfr[t] = *(const bf16x8*)&sB[wn + t * 16 + l16][quad * 8];
#pragma unroll
    for (int mt = 0; mt < 2; ++mt)
#pragma unroll
      for (int nt = 0; nt < 4; ++nt)
        acc[mt][nt] = __builtin_amdgcn_mfma_f32_16x16x32_bf16(af[mt], bfr[nt], acc[mt][nt], 0, 0, 0);
  }
#pragma unroll
  for (int mt = 0; mt < 2; ++mt) {
#pragma unroll
    for (int r = 0; r < 4; ++r) {
      const size_t m = m0 + wm + mt * 16 + quad * 4 + r;
      float* crow = C + m * DM;
#pragma unroll
      for (int nt = 0; nt < 4; ++nt)
        crow[n0 + wn + nt * 16 + l16] = acc[mt][nt][r];
    }
  }
}

// ---------------------------------------------------------------------------
// Flash attention, ALiBi, causal — uniform-chunk mapping.
// blockIdx.x = item in [0,80): chunk j of query-tile qt, covering KV tiles
// [j*8, min(j*8+8, qt+1)).
// Per-tile schedule (verified):
//   barrier1 -> ds_write K/V (tile t, regs loaded one tile ago)
//            -> issue global loads for tile t+1 (regs)
//   barrier2 -> compute tile t (QK^T, softmax, PV)
// ---------------------------------------------------------------------------
__global__ __launch_bounds__(256) void flash_alibi(const short* __restrict__ Q,
                                                   const short* __restrict__ K,
                                                   const short* __restrict__ V,
                                                   short* __restrict__ O,
                                                   short* __restrict__ Po,
                                                   float* __restrict__ Pl) {
  __shared__ short sK[64][72];             // [key][dim], padded
  __shared__ unsigned int sVt2[64][35];    // [dim][keypair], stride 35 words
  __shared__ short sP[4][16][74];          // per-wave P staging, stride 74

  const int tid  = threadIdx.x;
  const int lane = tid & 63, wv = tid >> 6;
  const int quad = lane >> 4, l16 = lane & 15;
  const int item = blockIdx.x;

  int qt, j;
  if (item < 8)       { qt = item;                j = 0; }
  else if (item < 24) { qt = 8 + (item - 8) / 2;  j = (item - 8) % 2; }
  else if (item < 48) { qt = 16 + (item - 24) / 3; j = (item - 24) % 3; }
  else                { qt = 24 + (item - 48) / 4; j = (item - 48) % 4; }

  const int n   = qt + 1;
  const int kts = j * 8;
  const int kte = (kts + 8 < n) ? (kts + 8) : n;

  const int h = blockIdx.y, b = blockIdx.z;
  const size_t base = (size_t)b * T_SEQ * DM + (size_t)h * HD;
  const int qi_base = qt * 64;

  // Q fragments (A-layout: m=l16, k=quad*8+j)
  bf16x8 qf[2];
  {
    const int qrow = qi_base + wv * 16 + l16;
    const short* qp = Q + base + (size_t)qrow * DM + quad * 8;
    qf[0] = *(const bf16x8*)(qp);
    qf[1] = *(const bf16x8*)(qp + 32);
  }

  const float slope = exp2f(-0.5f * (float)(h + 1));
  const float sl2   = slope * 1.4426950408889634f;     // slope * log2(e)
  const float C1    = 0.18033688011112042f;            // 0.125 * log2(e)
  const float bA1 = 16.f * sl2, bA2 = 32.f * sl2, bA3 = 48.f * sl2;
  const float c64 = 64.f * sl2;

  const int srow = tid >> 3;          // K staging row (0..31)
  const int scol = (tid & 7) << 3;    // K staging col
  const int kpair = tid >> 3;         // V staging key pair (0..31)
  const int d0 = (tid & 7) << 3;      // V staging dim group

  f32x4 oacc[4];
#pragma unroll
  for (int c = 0; c < 4; ++c) oacc[c] = (f32x4){0.f, 0.f, 0.f, 0.f};
  float lpart[4] = {0.f, 0.f, 0.f, 0.f};

  // running bias: bias0[r] = -sl2*(qi - k0 - l16) - 12*log2(e); += 64*sl2 per tile
  float bias0[4];
#pragma unroll
  for (int r = 0; r < 4; ++r) {
    const int qi = qi_base + wv * 16 + quad * 4 + r;
    bias0[r] = -sl2 * (float)(qi - kts * 64 - l16) - 17.312340490667562f;
  }

  // staged tile registers: loaded one tile EARLY, written to LDS in the
  // protected staging slot (between the two barriers).
  bf16x8 pka, pkb, pva, pvb;
  auto loadK = [&](int kt) {
    const short* g0 = K + base + (size_t)(kt * 64 + srow) * DM + scol;
    pka = *(const bf16x8*)g0;
    pkb = *(const bf16x8*)(g0 + 32 * DM);
  };
  auto loadV = [&](int kt) {
    const short* v0 = V + base + (size_t)(kt * 64 + 2 * kpair) * DM + d0;
    pva = *(const bf16x8*)v0;
    pvb = *(const bf16x8*)(v0 + DM);
  };
  auto writeK = [&]() {
    *(bf16x8*)&sK[srow][scol]      = pka;
    *(bf16x8*)&sK[srow + 32][scol] = pkb;
  };
  auto packV = [&]() {
    const unsigned* au = (const unsigned*)&pva;
    const unsigned* bu = (const unsigned*)&pvb;
#pragma unroll
    for (int e = 0; e < 4; ++e) {
      // {lo16 = pva.short[2e] (key 2kpair), hi16 = pvb.short[2e] (key 2kpair+1)}
      sVt2[d0 + 2 * e][kpair]     = __builtin_amdgcn_perm(bu[e], au[e], 0x05040100u);
      sVt2[d0 + 2 * e + 1][kpair] = __builtin_amdgcn_perm(bu[e], au[e], 0x07060302u);
    }
  };

  // prologue: issue first tile's loads (regs only; LDS writes in first tile)
  loadK(kts);
  loadV(kts);

  auto tile = [&](int kt, auto mc) {
    constexpr bool MASK = decltype(mc)::value;
    const int k0 = kt * 64;
    __syncthreads();   // protect sK/sVt2 from previous tile's readers
    writeK();          // stage tile t (vmcnt wait: loads are one tile old)
    packV();
    if (kt + 1 < kte) {          // issue next tile's loads (regs)
      loadK(kt + 1);
      loadV(kt + 1);
    }
    __syncthreads();   // staged LDS visible to all waves

    // S = Q K^T
    f32x4 sacc[4];
#pragma unroll
    for (int c = 0; c < 4; ++c) {
      f32x4 a = (f32x4){0.f, 0.f, 0.f, 0.f};
      a = __builtin_amdgcn_mfma_f32_16x16x32_bf16(
              qf[0], *(const bf16x8*)&sK[c * 16 + l16][quad * 8], a, 0, 0, 0);
      a = __builtin_amdgcn_mfma_f32_16x16x32_bf16(
              qf[1], *(const bf16x8*)&sK[c * 16 + l16][32 + quad * 8], a, 0, 0, 0);
      sacc[c] = a;
    }

    // softmax numerator: p = exp2(sacc*C1 + bias0[r] + bAdd[c]); mask diag only
    const float bAdd[4] = {0.f, bA1, bA2, bA3};
#pragma unroll
    for (int r = 0; r < 4; ++r) {
      float pv[4];
      int dist0r = 0;
      if constexpr (MASK)
        dist0r = qi_base + wv * 16 + quad * 4 + r - k0 - l16;
#pragma unroll
      for (int c = 0; c < 4; ++c) {
        float p = EXP2F(fmaf(sacc[c][r], C1, bias0[r] + bAdd[c]));
        if constexpr (MASK) p = (c * 16 <= dist0r) ? p : 0.0f;
        pv[c] = p;
      }
      lpart[r] += (pv[0] + pv[1]) + (pv[2] + pv[3]);
      const unsigned w01 = cvt_pk_bf16(pv[0], pv[1]);
      const unsigned w23 = cvt_pk_bf16(pv[2], pv[3]);
      short* pr = &sP[wv][quad * 4 + r][l16];
      pr[0]  = (short)(w01 & 0xffffu);
      pr[16] = (short)(w01 >> 16);
      pr[32] = (short)(w23 & 0xffffu);
      pr[48] = (short)(w23 >> 16);
    }
    // sP is wave-private; in-wave LDS ordering handled by lgkmcnt.

    // O += P V
#pragma unroll
    for (int s = 0; s < 2; ++s) {
      bf16x8 pfrag = *(const bf16x8*)&sP[wv][l16][s * 32 + quad * 8];
#pragma unroll
      for (int c = 0; c < 4; ++c) {
        const unsigned* vp = &sVt2[c * 16 + l16][s * 16 + quad * 4];
        bf16x4 vlo = *(const bf16x4*)vp;
        bf16x4 vhi = *(const bf16x4*)(vp + 2);
        bf16x8 vf = {vlo[0], vlo[1], vlo[2], vlo[3], vhi[0], vhi[1], vhi[2], vhi[3]};
        oacc[c] = __builtin_amdgcn_mfma_f32_16x16x32_bf16(pfrag, vf, oacc[c], 0, 0, 0);
      }
    }

#pragma unroll
    for (int r = 0; r < 4; ++r) bias0[r] += c64;   // k0 advances 64 next tile
  };

  // all tiles except the diagonal (last of the LAST chunk) are fully causal
  const int kfull = (kte == n) ? (kte - 1) : kte;
  for (int kt = kts; kt < kfull; ++kt) tile(kt, BoolT<false>{});
  if (kte == n) tile(n - 1, BoolT<true>{});   // diagonal tile: mask

  // epilogue: unnormalized O partial (bf16) + l partial (fp32)
  {
    const int pidx = (b * NH + h) * NCHB + item;
    short* po = Po + (size_t)pidx * 4096;   // [64 rows][64 dims]
    float* pl = Pl + (size_t)pidx * 64;
#pragma unroll
    for (int r = 0; r < 4; ++r) {
      float l = lpart[r];
#pragma unroll
      for (int off = 1; off < 16; off <<= 1) l += __shfl_xor(l, off);
      const int row = wv * 16 + quad * 4 + r;
      if (l16 == 0) pl[row] = l;
#pragma unroll
      for (int c = 0; c < 4; ++c)
        po[row * 64 + c * 16 + l16] = f2bf(oacc[c][r]);
    }
  }
}

// ---------------------------------------------------------------------------
// Combine: O[row] = (sum_j Oj)/(sum_j lj) -> bf16, for ALL query tiles.
// 65536 (b,h,qt,row) rows x 64 dims; 32 rows/block, 8 threads/row.
// chunks per qt: (qt>>3)+1; slab base cum(qt) = (g+1)*(4g + (qt&7)), g=qt>>3.
// ---------------------------------------------------------------------------
__global__ __launch_bounds__(256) void combine(const short* __restrict__ Po,
                                               const float* __restrict__ Pl,
                                               short* __restrict__ O) {
  const int g = blockIdx.x * 32 + (threadIdx.x >> 3);   // 0..65535
  const int d = (threadIdx.x & 7) << 3;
  const int row = g & 63;
  const int qt  = (g >> 6) & 31;
  const int h   = (g >> 11) & 15;
  const int b   = g >> 15;
  const int gq  = qt >> 3;
  const int nch = gq + 1;
  const int cum = (gq + 1) * (4 * gq + (qt & 7));
  const int sbase = (b * NH + h) * NCHB + cum;

  float l = 0.f;
  float acc[8] = {0.f, 0.f, 0.f, 0.f, 0.f, 0.f, 0.f, 0.f};
  for (int jj = 0; jj < nch; ++jj) {
    l += Pl[(size_t)(sbase + jj) * 64 + row];
    const short* p = Po + (size_t)(sbase + jj) * 4096 + row * 64 + d;
    bf16x8 a = *(const bf16x8*)p;
#pragma unroll
    for (int e = 0; e < 8; ++e) acc[e] += bf2f(a[e]);
  }
  const float inv = 1.0f / fmaxf(l, 1e-37f);
  const int qi = qt * 64 + row;
  short* orow = O + (size_t)b * T_SEQ * DM + (size_t)qi * DM + h * HD + d;
  bf16x8 o;
#pragma unroll
  for (int e = 0; e < 8; ++e) o[e] = f2bf(acc[e] * inv);
  *(bf16x8*)orow = o;
}

// ---------------------------------------------------------------------------
extern "C" void kernel_launch(void* const* d_in, const int* in_sizes, int n_in,
                              void* d_out, int out_size, void* d_ws, size_t ws_size,
                              hipStream_t stream) {
  float* out = (float*)d_out;   // fp32 output

  short* ws = (short*)d_ws;
  const size_t plane = (size_t)NROW * DM;   // 4M elements
  const size_t wsz   = (size_t)DM * DM;     // 1M elements
  const size_t nslab = (size_t)32 * NCHB;   // 2560 partial slabs
  short* xb  = ws;
  short* Wqb = xb + plane;
  short* Wkb = Wqb + wsz;
  short* Wvb = Wkb + wsz;
  short* Wob = Wvb + wsz;
  short* Qb  = Wob + wsz;
  short* Kb  = Qb + plane;
  short* Vb  = Kb + plane;
  short* Ab  = Vb + plane;
  short* Po  = Ab + plane;                  // 2560 slabs * 4096 bf16 = 21 MB
  float* Pl  = (float*)(Po + nslab * 4096); // 2560 * 64 fp32 = 655 KB

  dim3 blk(256);
  convert_all<<<8192, blk, 0, stream>>>(
      (const float*)d_in[0], (const float*)d_in[1], (const float*)d_in[2],
      (const float*)d_in[3], (const float*)d_in[4],
      xb, Wqb, Wkb, Wvb, Wob);

  gemm_qkv<<<dim3(NROW / 128, DM / 128, 3), blk, 0, stream>>>(xb, Wqb, Wkb, Wvb, Qb, Kb, Vb);
  flash_alibi<<<dim3(NCHB, NH, 2), blk, 0, stream>>>(Qb, Kb, Vb, Ab, Po, Pl);
  combine<<<2048, blk, 0, stream>>>(Po, Pl, Ab);
  gemm_out<<<dim3(NROW / 64, DM / 128, 1), blk, 0, stream>>>(Ab, Wob, out);
}

// Round 9
// 202.477 us; speedup vs baseline: 1.5491x; 1.5491x over previous
//
#include <hip/hip_runtime.h>
#include <math.h>

// ALiBi attention: B=2, T=2048, D=1024, H=16, hd=64. fp32 in/out.
// Round 16: revert flash to round-14 verified LDS layout (strides 34/72 —
// round-15's pads broke 8B/16B LDS vector alignment -> 3.3x regression).
// One change: gemm_qkv retiled to the round-14-verified 64x128 body
// (templated gemm_out body), grid 768 -> 1536 blocks (6/CU).

#define T_SEQ 2048
#define DM    1024
#define NH    16
#define HD    64
#define NROW  4096   // B*T
#define NCHB  80     // chunks per (h,b): qt/8 -> 1,2,3,4 chunks

typedef __attribute__((ext_vector_type(8))) short bf16x8;
typedef __attribute__((ext_vector_type(4))) short bf16x4;
typedef __attribute__((ext_vector_type(4))) float f32x4;

template <bool M> struct BoolT { static constexpr bool value = M; };

__device__ __forceinline__ short f2bf(float f) {
  unsigned u = __float_as_uint(f);
  u += 0x7FFFu + ((u >> 16) & 1u);
  return (short)(u >> 16);
}
__device__ __forceinline__ float bf2f(short s) {
  return __uint_as_float(((unsigned)(unsigned short)s) << 16);
}

// RNE pack of two f32 -> {lo16=bf16(a), hi16=bf16(b)} in one instruction.
__device__ __forceinline__ unsigned cvt_pk_bf16(float a, float b) {
  unsigned r;
  asm("v_cvt_pk_bf16_f32 %0, %1, %2" : "=v"(r) : "v"(a), "v"(b));
  return r;
}

#if __has_builtin(__builtin_amdgcn_exp2f)
#define EXP2F(x) __builtin_amdgcn_exp2f(x)
#else
#define EXP2F(x) exp2f(x)
#endif

// async global->LDS, 16B per lane; lds dest is wave-uniform base + lane*16B.
__device__ __forceinline__ void gload_lds16(short* lds, const short* g) {
  __builtin_amdgcn_global_load_lds((const __attribute__((address_space(1))) void*)g,
                                   (__attribute__((address_space(3))) void*)lds, 16, 0, 0);
}

// ---------------------------------------------------------------------------
// Merged fp32->bf16 conversion: x (4M) + 4 weights (1M each), 2M float4 groups.
// ---------------------------------------------------------------------------
__global__ __launch_bounds__(256) void convert_all(
    const float* __restrict__ x,  const float* __restrict__ wq,
    const float* __restrict__ wk, const float* __restrict__ wv,
    const float* __restrict__ wo,
    short* __restrict__ xb,  short* __restrict__ wqb, short* __restrict__ wkb,
    short* __restrict__ wvb, short* __restrict__ wob) {
  const int i = blockIdx.x * 256 + threadIdx.x;
  const float* s; short* d; int off;
  if (i < (1 << 20)) { s = x; d = xb; off = i; }
  else {
    const int j = i - (1 << 20);
    const int w = j >> 18;
    off = j & ((1 << 18) - 1);
    s = (w == 0) ? wq : (w == 1) ? wk : (w == 2) ? wv : wo;
    d = (w == 0) ? wqb : (w == 1) ? wkb : (w == 2) ? wvb : wob;
  }
  const float4 v = ((const float4*)s)[off];
  bf16x4 o = {f2bf(v.x), f2bf(v.y), f2bf(v.z), f2bf(v.w)};
  *(bf16x4*)(d + 4 * (size_t)off) = o;
}

// ---------------------------------------------------------------------------
// 64x128 GEMM tile (round-14 verified body, now templated on OutT):
// grid (M/64, N/128); 4 waves as 2x2, each wave 32x64 (acc[2][4]).
// Staging: 12 chunks of 16 rows ([A:4][B:8]), 3 chunks per wave.
// ---------------------------------------------------------------------------
template <typename OutT>
__device__ __forceinline__ void gemm64_body(const short* __restrict__ A,
                                            const short* __restrict__ W,
                                            OutT* __restrict__ C) {
  __shared__ short sA[64][32];
  __shared__ short sB[128][32];
  const int tid  = threadIdx.x;
  const int lane = tid & 63, wv = tid >> 6;
  const int quad = lane >> 4, l16 = lane & 15;
  const int wm = (wv >> 1) * 32, wn = (wv & 1) * 64;
  const size_t m0 = (size_t)blockIdx.x * 64, n0 = (size_t)blockIdx.y * 128;

  f32x4 acc[2][4];
#pragma unroll
  for (int i = 0; i < 2; ++i)
#pragma unroll
    for (int j = 0; j < 4; ++j) acc[i][j] = (f32x4){0.f, 0.f, 0.f, 0.f};

  const int grow = lane >> 2;
  const int gcol = (lane & 3) << 3;

  for (int k0 = 0; k0 < DM; k0 += 32) {
    __syncthreads();
#pragma unroll
    for (int cc = 0; cc < 3; ++cc) {
      const int i = wv * 3 + cc;   // 0..11, wave-uniform per call
      short* dst = (i < 4) ? &sA[i * 16][0] : &sB[(i - 4) * 16][0];
      const short* src = (i < 4)
          ? A + (m0 + i * 16 + grow) * DM + k0 + gcol
          : W + (n0 + (i - 4) * 16 + grow) * DM + k0 + gcol;
      gload_lds16(dst, src);
    }
    __syncthreads();

    bf16x8 af[2], bfr[4];
#pragma unroll
    for (int t = 0; t < 2; ++t)
      af[t] = *(const bf16x8*)&sA[wm + t * 16 + l16][quad * 8];
#pragma unroll
    for (int t = 0; t < 4; ++t)
      bfr[t] = *(const bf16x8*)&sB[wn + t * 16 + l16][quad * 8];
#pragma unroll
    for (int mt = 0; mt < 2; ++mt)
#pragma unroll
      for (int nt = 0; nt < 4; ++nt)
        acc[mt][nt] = __builtin_amdgcn_mfma_f32_16x16x32_bf16(af[mt], bfr[nt], acc[mt][nt], 0, 0, 0);
  }
#pragma unroll
  for (int mt = 0; mt < 2; ++mt) {
#pragma unroll
    for (int r = 0; r < 4; ++r) {
      const size_t m = m0 + wm + mt * 16 + quad * 4 + r;
      OutT* crow = C + m * DM;
#pragma unroll
      for (int nt = 0; nt < 4; ++nt) {
        const float v = acc[mt][nt][r];
        if constexpr (sizeof(OutT) == 2)
          crow[n0 + wn + nt * 16 + l16] = f2bf(v);
        else
          crow[n0 + wn + nt * 16 + l16] = v;
      }
    }
  }
}

__global__ __launch_bounds__(256) void gemm_qkv(
    const short* __restrict__ x,
    const short* __restrict__ Wq, const short* __restrict__ Wk, const short* __restrict__ Wv,
    short* __restrict__ Qb, short* __restrict__ Kb, short* __restrict__ Vb) {
  const short* W = (blockIdx.z == 0) ? Wq : (blockIdx.z == 1) ? Wk : Wv;
  short*       C = (blockIdx.z == 0) ? Qb : (blockIdx.z == 1) ? Kb : Vb;
  gemm64_body<short>(x, W, C);
}

__global__ __launch_bounds__(256) void gemm_out(const short* __restrict__ A,
                                                const short* __restrict__ W,
                                                float* __restrict__ C) {
  gemm64_body<float>(A, W, C);
}

// ---------------------------------------------------------------------------
// Flash attention, ALiBi, causal — uniform-chunk mapping.
// blockIdx.x = item in [0,80): chunk j of query-tile qt, covering KV tiles
// [j*8, min(j*8+8, qt+1)).
// Per-tile schedule (round-14 VERBATIM, verified):
//   barrier1 -> ds_write K/V (tile t, regs loaded one tile ago)
//            -> issue global loads for tile t+1 (regs)
//   barrier2 -> compute tile t (QK^T, softmax, PV)
// LDS strides 34 words / 72 shorts: pads MUST stay multiples of the widest
// vector access (round-15 lesson: odd pads broke 8/16B alignment, 3.3x).
// ---------------------------------------------------------------------------
__global__ __launch_bounds__(256) void flash_alibi(const short* __restrict__ Q,
                                                   const short* __restrict__ K,
                                                   const short* __restrict__ V,
                                                   short* __restrict__ O,
                                                   short* __restrict__ Po,
                                                   float* __restrict__ Pl) {
  __shared__ short sK[64][72];             // [key][dim], padded
  __shared__ unsigned int sVt2[64][34];    // [dim][keypair]
  __shared__ short sP[4][16][72];          // per-wave P staging

  const int tid  = threadIdx.x;
  const int lane = tid & 63, wv = tid >> 6;
  const int quad = lane >> 4, l16 = lane & 15;
  const int item = blockIdx.x;

  int qt, j;
  if (item < 8)       { qt = item;                j = 0; }
  else if (item < 24) { qt = 8 + (item - 8) / 2;  j = (item - 8) % 2; }
  else if (item < 48) { qt = 16 + (item - 24) / 3; j = (item - 24) % 3; }
  else                { qt = 24 + (item - 48) / 4; j = (item - 48) % 4; }

  const int n   = qt + 1;
  const int kts = j * 8;
  const int kte = (kts + 8 < n) ? (kts + 8) : n;

  const int h = blockIdx.y, b = blockIdx.z;
  const size_t base = (size_t)b * T_SEQ * DM + (size_t)h * HD;
  const int qi_base = qt * 64;

  // Q fragments (A-layout: m=l16, k=quad*8+j)
  bf16x8 qf[2];
  {
    const int qrow = qi_base + wv * 16 + l16;
    const short* qp = Q + base + (size_t)qrow * DM + quad * 8;
    qf[0] = *(const bf16x8*)(qp);
    qf[1] = *(const bf16x8*)(qp + 32);
  }

  const float slope = exp2f(-0.5f * (float)(h + 1));
  const float sl2   = slope * 1.4426950408889634f;     // slope * log2(e)
  const float C1    = 0.18033688011112042f;            // 0.125 * log2(e)
  const float bA1 = 16.f * sl2, bA2 = 32.f * sl2, bA3 = 48.f * sl2;
  const float c64 = 64.f * sl2;

  const int srow = tid >> 3;          // K staging row (0..31)
  const int scol = (tid & 7) << 3;    // K staging col
  const int kpair = tid >> 3;         // V staging key pair (0..31)
  const int d0 = (tid & 7) << 3;      // V staging dim group

  f32x4 oacc[4];
#pragma unroll
  for (int c = 0; c < 4; ++c) oacc[c] = (f32x4){0.f, 0.f, 0.f, 0.f};
  float lpart[4] = {0.f, 0.f, 0.f, 0.f};

  // running bias: bias0[r] = -sl2*(qi - k0 - l16) - 12*log2(e); += 64*sl2 per tile
  float bias0[4];
#pragma unroll
  for (int r = 0; r < 4; ++r) {
    const int qi = qi_base + wv * 16 + quad * 4 + r;
    bias0[r] = -sl2 * (float)(qi - kts * 64 - l16) - 17.312340490667562f;
  }

  // staged tile registers: loaded one tile EARLY, written to LDS in the
  // protected staging slot (between the two barriers).
  bf16x8 pka, pkb, pva, pvb;
  auto loadK = [&](int kt) {
    const short* g0 = K + base + (size_t)(kt * 64 + srow) * DM + scol;
    pka = *(const bf16x8*)g0;
    pkb = *(const bf16x8*)(g0 + 32 * DM);
  };
  auto loadV = [&](int kt) {
    const short* v0 = V + base + (size_t)(kt * 64 + 2 * kpair) * DM + d0;
    pva = *(const bf16x8*)v0;
    pvb = *(const bf16x8*)(v0 + DM);
  };
  auto writeK = [&]() {
    *(bf16x8*)&sK[srow][scol]      = pka;
    *(bf16x8*)&sK[srow + 32][scol] = pkb;
  };
  auto packV = [&]() {
    const unsigned* au = (const unsigned*)&pva;
    const unsigned* bu = (const unsigned*)&pvb;
#pragma unroll
    for (int e = 0; e < 4; ++e) {
      // {lo16 = pva.short[2e] (key 2kpair), hi16 = pvb.short[2e] (key 2kpair+1)}
      sVt2[d0 + 2 * e][kpair]     = __builtin_amdgcn_perm(bu[e], au[e], 0x05040100u);
      sVt2[d0 + 2 * e + 1][kpair] = __builtin_amdgcn_perm(bu[e], au[e], 0x07060302u);
    }
  };

  // prologue: issue first tile's loads (regs only; LDS writes in first tile)
  loadK(kts);
  loadV(kts);

  auto tile = [&](int kt, auto mc) {
    constexpr bool MASK = decltype(mc)::value;
    const int k0 = kt * 64;
    __syncthreads();   // protect sK/sVt2 from previous tile's readers
    writeK();          // stage tile t (vmcnt wait: loads are one tile old)
    packV();
    if (kt + 1 < kte) {          // issue next tile's loads (regs)
      loadK(kt + 1);
      loadV(kt + 1);
    }
    __syncthreads();   // staged LDS visible to all waves

    // S = Q K^T
    f32x4 sacc[4];
#pragma unroll
    for (int c = 0; c < 4; ++c) {
      f32x4 a = (f32x4){0.f, 0.f, 0.f, 0.f};
      a = __builtin_amdgcn_mfma_f32_16x16x32_bf16(
              qf[0], *(const bf16x8*)&sK[c * 16 + l16][quad * 8], a, 0, 0, 0);
      a = __builtin_amdgcn_mfma_f32_16x16x32_bf16(
              qf[1], *(const bf16x8*)&sK[c * 16 + l16][32 + quad * 8], a, 0, 0, 0);
      sacc[c] = a;
    }

    // softmax numerator: p = exp2(sacc*C1 + bias0[r] + bAdd[c]); mask diag only
    const float bAdd[4] = {0.f, bA1, bA2, bA3};
#pragma unroll
    for (int r = 0; r < 4; ++r) {
      float pv[4];
      int dist0r = 0;
      if constexpr (MASK)
        dist0r = qi_base + wv * 16 + quad * 4 + r - k0 - l16;
#pragma unroll
      for (int c = 0; c < 4; ++c) {
        float p = EXP2F(fmaf(sacc[c][r], C1, bias0[r] + bAdd[c]));
        if constexpr (MASK) p = (c * 16 <= dist0r) ? p : 0.0f;
        pv[c] = p;
      }
      lpart[r] += (pv[0] + pv[1]) + (pv[2] + pv[3]);
      const unsigned w01 = cvt_pk_bf16(pv[0], pv[1]);
      const unsigned w23 = cvt_pk_bf16(pv[2], pv[3]);
      short* pr = &sP[wv][quad * 4 + r][l16];
      pr[0]  = (short)(w01 & 0xffffu);
      pr[16] = (short)(w01 >> 16);
      pr[32] = (short)(w23 & 0xffffu);
      pr[48] = (short)(w23 >> 16);
    }
    // sP is wave-private; in-wave LDS ordering handled by lgkmcnt.

    // O += P V
#pragma unroll
    for (int s = 0; s < 2; ++s) {
      bf16x8 pfrag = *(const bf16x8*)&sP[wv][l16][s * 32 + quad * 8];
#pragma unroll
      for (int c = 0; c < 4; ++c) {
        const unsigned* vp = &sVt2[c * 16 + l16][s * 16 + quad * 4];
        bf16x4 vlo = *(const bf16x4*)vp;
        bf16x4 vhi = *(const bf16x4*)(vp + 2);
        bf16x8 vf = {vlo[0], vlo[1], vlo[2], vlo[3], vhi[0], vhi[1], vhi[2], vhi[3]};
        oacc[c] = __builtin_amdgcn_mfma_f32_16x16x32_bf16(pfrag, vf, oacc[c], 0, 0, 0);
      }
    }

#pragma unroll
    for (int r = 0; r < 4; ++r) bias0[r] += c64;   // k0 advances 64 next tile
  };

  // all tiles except the diagonal (last of the LAST chunk) are fully causal
  const int kfull = (kte == n) ? (kte - 1) : kte;
  for (int kt = kts; kt < kfull; ++kt) tile(kt, BoolT<false>{});
  if (kte == n) tile(n - 1, BoolT<true>{});   // diagonal tile: mask

  // epilogue: unnormalized O partial (bf16) + l partial (fp32)
  {
    const int pidx = (b * NH + h) * NCHB + item;
    short* po = Po + (size_t)pidx * 4096;   // [64 rows][64 dims]
    float* pl = Pl + (size_t)pidx * 64;
#pragma unroll
    for (int r = 0; r < 4; ++r) {
      float l = lpart[r];
#pragma unroll
      for (int off = 1; off < 16; off <<= 1) l += __shfl_xor(l, off);
      const int row = wv * 16 + quad * 4 + r;
      if (l16 == 0) pl[row] = l;
#pragma unroll
      for (int c = 0; c < 4; ++c)
        po[row * 64 + c * 16 + l16] = f2bf(oacc[c][r]);
    }
  }
}

// ---------------------------------------------------------------------------
// Combine: O[row] = (sum_j Oj)/(sum_j lj) -> bf16, for ALL query tiles.
// 65536 (b,h,qt,row) rows x 64 dims; 32 rows/block, 8 threads/row.
// chunks per qt: (qt>>3)+1; slab base cum(qt) = (g+1)*(4g + (qt&7)), g=qt>>3.
// ---------------------------------------------------------------------------
__global__ __launch_bounds__(256) void combine(const short* __restrict__ Po,
                                               const float* __restrict__ Pl,
                                               short* __restrict__ O) {
  const int g = blockIdx.x * 32 + (threadIdx.x >> 3);   // 0..65535
  const int d = (threadIdx.x & 7) << 3;
  const int row = g & 63;
  const int qt  = (g >> 6) & 31;
  const int h   = (g >> 11) & 15;
  const int b   = g >> 15;
  const int gq  = qt >> 3;
  const int nch = gq + 1;
  const int cum = (gq + 1) * (4 * gq + (qt & 7));
  const int sbase = (b * NH + h) * NCHB + cum;

  float l = 0.f;
  float acc[8] = {0.f, 0.f, 0.f, 0.f, 0.f, 0.f, 0.f, 0.f};
  for (int jj = 0; jj < nch; ++jj) {
    l += Pl[(size_t)(sbase + jj) * 64 + row];
    const short* p = Po + (size_t)(sbase + jj) * 4096 + row * 64 + d;
    bf16x8 a = *(const bf16x8*)p;
#pragma unroll
    for (int e = 0; e < 8; ++e) acc[e] += bf2f(a[e]);
  }
  const float inv = 1.0f / fmaxf(l, 1e-37f);
  const int qi = qt * 64 + row;
  short* orow = O + (size_t)b * T_SEQ * DM + (size_t)qi * DM + h * HD + d;
  bf16x8 o;
#pragma unroll
  for (int e = 0; e < 8; ++e) o[e] = f2bf(acc[e] * inv);
  *(bf16x8*)orow = o;
}

// ---------------------------------------------------------------------------
extern "C" void kernel_launch(void* const* d_in, const int* in_sizes, int n_in,
                              void* d_out, int out_size, void* d_ws, size_t ws_size,
                              hipStream_t stream) {
  float* out = (float*)d_out;   // fp32 output

  short* ws = (short*)d_ws;
  const size_t plane = (size_t)NROW * DM;   // 4M elements
  const size_t wsz   = (size_t)DM * DM;     // 1M elements
  const size_t nslab = (size_t)32 * NCHB;   // 2560 partial slabs
  short* xb  = ws;
  short* Wqb = xb + plane;
  short* Wkb = Wqb + wsz;
  short* Wvb = Wkb + wsz;
  short* Wob = Wvb + wsz;
  short* Qb  = Wob + wsz;
  short* Kb  = Qb + plane;
  short* Vb  = Kb + plane;
  short* Ab  = Vb + plane;
  short* Po  = Ab + plane;                  // 2560 slabs * 4096 bf16 = 21 MB
  float* Pl  = (float*)(Po + nslab * 4096); // 2560 * 64 fp32 = 655 KB

  dim3 blk(256);
  convert_all<<<8192, blk, 0, stream>>>(
      (const float*)d_in[0], (const float*)d_in[1], (const float*)d_in[2],
      (const float*)d_in[3], (const float*)d_in[4],
      xb, Wqb, Wkb, Wvb, Wob);

  gemm_qkv<<<dim3(NROW / 64, DM / 128, 3), blk, 0, stream>>>(xb, Wqb, Wkb, Wvb, Qb, Kb, Vb);
  flash_alibi<<<dim3(NCHB, NH, 2), blk, 0, stream>>>(Qb, Kb, Vb, Ab, Po, Pl);
  combine<<<2048, blk, 0, stream>>>(Po, Pl, Ab);
  gemm_out<<<dim3(NROW / 64, DM / 128, 1), blk, 0, stream>>>(Ab, Wob, out);
}

// Round 10
// 179.500 us; speedup vs baseline: 1.7474x; 1.1280x over previous
//
#include <hip/hip_runtime.h>
#include <math.h>

// ALiBi attention: B=2, T=2048, D=1024, H=16, hd=64. fp32 in/out.
// Round 17: (a) revert gemm_qkv to round-14 128x128 body (64x128 regressed).
// (b) flash: swapped QK^T (mfma(K,Q)) -> P lane-local per query; PV A-frag
// assembled in registers via cvt_pk_bf16 + v_permlane32_swap_b32 with a
// matching key-order permutation in sVt2 column indexing. sP deleted
// (-16 ds_write_b16 -2 ds_read_b128 per thread per tile; LDS 27->18 KB).
// DS pipe was the measured bottleneck (~80% busy by instruction accounting).

#define T_SEQ 2048
#define DM    1024
#define NH    16
#define HD    64
#define NROW  4096   // B*T
#define NCHB  80     // chunks per (h,b): qt/8 -> 1,2,3,4 chunks

typedef __attribute__((ext_vector_type(8))) short bf16x8;
typedef __attribute__((ext_vector_type(4))) short bf16x4;
typedef __attribute__((ext_vector_type(4))) float f32x4;

template <bool M> struct BoolT { static constexpr bool value = M; };

__device__ __forceinline__ short f2bf(float f) {
  unsigned u = __float_as_uint(f);
  u += 0x7FFFu + ((u >> 16) & 1u);
  return (short)(u >> 16);
}
__device__ __forceinline__ float bf2f(short s) {
  return __uint_as_float(((unsigned)(unsigned short)s) << 16);
}

// RNE pack of two f32 -> {lo16=bf16(a), hi16=bf16(b)} in one instruction.
__device__ __forceinline__ unsigned cvt_pk_bf16(float a, float b) {
  unsigned r;
  asm("v_cvt_pk_bf16_f32 %0, %1, %2" : "=v"(r) : "v"(a), "v"(b));
  return r;
}

// v_permlane32_swap_b32 a, b: a.hi32lanes <-> b.lo32lanes.
// After: lanes 0-31: a'=a(own), b'=a@(lane+32); lanes 32-63: a'=b@(lane-32), b'=b(own).
__device__ __forceinline__ void permlane32_swap(unsigned &a, unsigned &b) {
  asm("v_permlane32_swap_b32 %0, %1" : "+v"(a), "+v"(b));
}

#if __has_builtin(__builtin_amdgcn_exp2f)
#define EXP2F(x) __builtin_amdgcn_exp2f(x)
#else
#define EXP2F(x) exp2f(x)
#endif

// async global->LDS, 16B per lane; lds dest is wave-uniform base + lane*16B.
__device__ __forceinline__ void gload_lds16(short* lds, const short* g) {
  __builtin_amdgcn_global_load_lds((const __attribute__((address_space(1))) void*)g,
                                   (__attribute__((address_space(3))) void*)lds, 16, 0, 0);
}

// ---------------------------------------------------------------------------
// Merged fp32->bf16 conversion: x (4M) + 4 weights (1M each), 2M float4 groups.
// ---------------------------------------------------------------------------
__global__ __launch_bounds__(256) void convert_all(
    const float* __restrict__ x,  const float* __restrict__ wq,
    const float* __restrict__ wk, const float* __restrict__ wv,
    const float* __restrict__ wo,
    short* __restrict__ xb,  short* __restrict__ wqb, short* __restrict__ wkb,
    short* __restrict__ wvb, short* __restrict__ wob) {
  const int i = blockIdx.x * 256 + threadIdx.x;
  const float* s; short* d; int off;
  if (i < (1 << 20)) { s = x; d = xb; off = i; }
  else {
    const int j = i - (1 << 20);
    const int w = j >> 18;
    off = j & ((1 << 18) - 1);
    s = (w == 0) ? wq : (w == 1) ? wk : (w == 2) ? wv : wo;
    d = (w == 0) ? wqb : (w == 1) ? wkb : (w == 2) ? wvb : wob;
  }
  const float4 v = ((const float4*)s)[off];
  bf16x4 o = {f2bf(v.x), f2bf(v.y), f2bf(v.z), f2bf(v.w)};
  *(bf16x4*)(d + 4 * (size_t)off) = o;
}

// ---------------------------------------------------------------------------
// GEMM 128x128, BK=32 (round-5/14 verified): C[m][n] = sum_k A[m][k]*W[n][k].
// ---------------------------------------------------------------------------
template <typename OutT>
__device__ __forceinline__ void gemm_body(const short* __restrict__ A,
                                          const short* __restrict__ W,
                                          OutT* __restrict__ C) {
  __shared__ short sA[128][32];
  __shared__ short sB[128][32];
  const int tid  = threadIdx.x;
  const int lane = tid & 63, wv = tid >> 6;
  const int quad = lane >> 4, l16 = lane & 15;
  const int wm = (wv >> 1) * 64, wn = (wv & 1) * 64;
  const size_t m0 = (size_t)blockIdx.x * 128, n0 = (size_t)blockIdx.y * 128;

  f32x4 acc[4][4];
#pragma unroll
  for (int i = 0; i < 4; ++i)
#pragma unroll
    for (int j = 0; j < 4; ++j) acc[i][j] = (f32x4){0.f, 0.f, 0.f, 0.f};

  const int grow = lane >> 2;
  const int gcol = (lane & 3) << 3;

  for (int k0 = 0; k0 < DM; k0 += 32) {
    __syncthreads();
    {
      const short* ga = A + (m0 + wv * 32 + grow) * DM + k0 + gcol;
      gload_lds16(&sA[wv * 32][0],      ga);
      gload_lds16(&sA[wv * 32 + 16][0], ga + 16 * DM);
      const short* gb = W + (n0 + wv * 32 + grow) * DM + k0 + gcol;
      gload_lds16(&sB[wv * 32][0],      gb);
      gload_lds16(&sB[wv * 32 + 16][0], gb + 16 * DM);
    }
    __syncthreads();

    bf16x8 af[4], bfr[4];
#pragma unroll
    for (int t = 0; t < 4; ++t) {
      af[t]  = *(const bf16x8*)&sA[wm + t * 16 + l16][quad * 8];
      bfr[t] = *(const bf16x8*)&sB[wn + t * 16 + l16][quad * 8];
    }
#pragma unroll
    for (int mt = 0; mt < 4; ++mt)
#pragma unroll
      for (int nt = 0; nt < 4; ++nt)
        acc[mt][nt] = __builtin_amdgcn_mfma_f32_16x16x32_bf16(af[mt], bfr[nt], acc[mt][nt], 0, 0, 0);
  }
#pragma unroll
  for (int mt = 0; mt < 4; ++mt) {
#pragma unroll
    for (int r = 0; r < 4; ++r) {
      const size_t m = m0 + wm + mt * 16 + quad * 4 + r;
      OutT* crow = C + m * DM;
#pragma unroll
      for (int nt = 0; nt < 4; ++nt) {
        const float v = acc[mt][nt][r];
        if constexpr (sizeof(OutT) == 2)
          crow[n0 + wn + nt * 16 + l16] = f2bf(v);
        else
          crow[n0 + wn + nt * 16 + l16] = v;
      }
    }
  }
}

__global__ __launch_bounds__(256) void gemm_qkv(
    const short* __restrict__ x,
    const short* __restrict__ Wq, const short* __restrict__ Wk, const short* __restrict__ Wv,
    short* __restrict__ Qb, short* __restrict__ Kb, short* __restrict__ Vb) {
  const short* W = (blockIdx.z == 0) ? Wq : (blockIdx.z == 1) ? Wk : Wv;
  short*       C = (blockIdx.z == 0) ? Qb : (blockIdx.z == 1) ? Kb : Vb;
  gemm_body<short>(x, W, C);
}

// ---------------------------------------------------------------------------
// Output GEMM: 64x128 tile (round-14 verified; fixes 1-block/CU cliff).
// ---------------------------------------------------------------------------
__global__ __launch_bounds__(256) void gemm_out(const short* __restrict__ A,
                                                const short* __restrict__ W,
                                                float* __restrict__ C) {
  __shared__ short sA[64][32];
  __shared__ short sB[128][32];
  const int tid  = threadIdx.x;
  const int lane = tid & 63, wv = tid >> 6;
  const int quad = lane >> 4, l16 = lane & 15;
  const int wm = (wv >> 1) * 32, wn = (wv & 1) * 64;
  const size_t m0 = (size_t)blockIdx.x * 64, n0 = (size_t)blockIdx.y * 128;

  f32x4 acc[2][4];
#pragma unroll
  for (int i = 0; i < 2; ++i)
#pragma unroll
    for (int j = 0; j < 4; ++j) acc[i][j] = (f32x4){0.f, 0.f, 0.f, 0.f};

  const int grow = lane >> 2;
  const int gcol = (lane & 3) << 3;

  for (int k0 = 0; k0 < DM; k0 += 32) {
    __syncthreads();
#pragma unroll
    for (int cc = 0; cc < 3; ++cc) {
      const int i = wv * 3 + cc;   // 0..11, wave-uniform per call
      short* dst = (i < 4) ? &sA[i * 16][0] : &sB[(i - 4) * 16][0];
      const short* src = (i < 4)
          ? A + (m0 + i * 16 + grow) * DM + k0 + gcol
          : W + (n0 + (i - 4) * 16 + grow) * DM + k0 + gcol;
      gload_lds16(dst, src);
    }
    __syncthreads();

    bf16x8 af[2], bfr[4];
#pragma unroll
    for (int t = 0; t < 2; ++t)
      af[t] = *(const bf16x8*)&sA[wm + t * 16 + l16][quad * 8];
#pragma unroll
    for (int t = 0; t < 4; ++t)
      bfr[t] = *(const bf16x8*)&sB[wn + t * 16 + l16][quad * 8];
#pragma unroll
    for (int mt = 0; mt < 2; ++mt)
#pragma unroll
      for (int nt = 0; nt < 4; ++nt)
        acc[mt][nt] = __builtin_amdgcn_mfma_f32_16x16x32_bf16(af[mt], bfr[nt], acc[mt][nt], 0, 0, 0);
  }
#pragma unroll
  for (int mt = 0; mt < 2; ++mt) {
#pragma unroll
    for (int r = 0; r < 4; ++r) {
      const size_t m = m0 + wm + mt * 16 + quad * 4 + r;
      float* crow = C + m * DM;
#pragma unroll
      for (int nt = 0; nt < 4; ++nt)
        crow[n0 + wn + nt * 16 + l16] = acc[mt][nt][r];
    }
  }
}

// ---------------------------------------------------------------------------
// Flash attention, ALiBi, causal — uniform-chunk mapping, swapped QK^T.
// blockIdx.x = item in [0,80): chunk j of query-tile qt, KV tiles
// [j*8, min(j*8+8, qt+1)). Per-tile schedule (round-12 verified):
//   barrier1 -> ds_write K/V (tile t, regs loaded one tile ago)
//            -> issue global loads for tile t+1 (regs)
//   barrier2 -> compute tile t
// Compute: S^T = mfma(K,Q): lane(l16,quad) holds S[key=c*16+quad*4+r][q=l16].
// Softmax in-lane; P->bf16 via cvt_pk; PV A-frag assembled with two
// permlane32_swap per 32-key half. Key order in PV is permuted; sVt2 column
// permutation col(p)=(p&3)*2+((p>>2)&1)+(p&~7) makes V reads match (same
// contiguous b64 reads as before). No sP buffer.
// ---------------------------------------------------------------------------
__global__ __launch_bounds__(256) void flash_alibi(const short* __restrict__ Q,
                                                   const short* __restrict__ K,
                                                   const short* __restrict__ V,
                                                   short* __restrict__ O,
                                                   short* __restrict__ Po,
                                                   float* __restrict__ Pl) {
  __shared__ short sK[64][72];             // [key][dim], padded
  __shared__ unsigned int sVt2[64][34];    // [dim][keypair-permuted]

  const int tid  = threadIdx.x;
  const int lane = tid & 63, wv = tid >> 6;
  const int quad = lane >> 4, l16 = lane & 15;
  const int item = blockIdx.x;

  int qt, j;
  if (item < 8)       { qt = item;                j = 0; }
  else if (item < 24) { qt = 8 + (item - 8) / 2;  j = (item - 8) % 2; }
  else if (item < 48) { qt = 16 + (item - 24) / 3; j = (item - 24) % 3; }
  else                { qt = 24 + (item - 48) / 4; j = (item - 48) % 4; }

  const int n   = qt + 1;
  const int kts = j * 8;
  const int kte = (kts + 8 < n) ? (kts + 8) : n;

  const int h = blockIdx.y, b = blockIdx.z;
  const size_t base = (size_t)b * T_SEQ * DM + (size_t)h * HD;
  const int qi_base = qt * 64;

  // Q fragments (identical layout serves as B-operand: col=l16, k=quad*8+j)
  bf16x8 qf[2];
  {
    const int qrow = qi_base + wv * 16 + l16;
    const short* qp = Q + base + (size_t)qrow * DM + quad * 8;
    qf[0] = *(const bf16x8*)(qp);
    qf[1] = *(const bf16x8*)(qp + 32);
  }

  const float slope = exp2f(-0.5f * (float)(h + 1));
  const float sl2   = slope * 1.4426950408889634f;     // slope * log2(e)
  const float C1    = 0.18033688011112042f;            // 0.125 * log2(e)
  const float bA1 = 16.f * sl2, bA2 = 32.f * sl2, bA3 = 48.f * sl2;
  const float c64 = 64.f * sl2;

  const int srow = tid >> 3;          // K staging row (0..31)
  const int scol = (tid & 7) << 3;    // K staging col
  const int kp   = tid >> 3;          // V staging key pair (0..31)
  const int d0   = (tid & 7) << 3;    // V staging dim group
  // PV key-order permutation: physical pair p stored at column col(p).
  const int vcol = ((kp & 3) << 1) + ((kp >> 2) & 1) + (kp & ~7);

  f32x4 oacc[4];
#pragma unroll
  for (int c = 0; c < 4; ++c) oacc[c] = (f32x4){0.f, 0.f, 0.f, 0.f};
  float lsum = 0.f;                   // partial row-sum for query l16

  const int qi = qi_base + wv * 16 + l16;   // this lane's query row
  // bias0[r] = -sl2*(qi - kj) - 12*log2(e) at kj = kts*64 + quad*4 + r
  float bias0[4];
#pragma unroll
  for (int r = 0; r < 4; ++r)
    bias0[r] = sl2 * (float)(kts * 64 + quad * 4 + r - qi) - 17.312340490667562f;

  // staged tile registers: loaded one tile EARLY, written to LDS in the
  // protected staging slot (between the two barriers).
  bf16x8 pka, pkb, pva, pvb;
  auto loadK = [&](int kt) {
    const short* g0 = K + base + (size_t)(kt * 64 + srow) * DM + scol;
    pka = *(const bf16x8*)g0;
    pkb = *(const bf16x8*)(g0 + 32 * DM);
  };
  auto loadV = [&](int kt) {
    const short* v0 = V + base + (size_t)(kt * 64 + 2 * kp) * DM + d0;
    pva = *(const bf16x8*)v0;
    pvb = *(const bf16x8*)(v0 + DM);
  };
  auto writeK = [&]() {
    *(bf16x8*)&sK[srow][scol]      = pka;
    *(bf16x8*)&sK[srow + 32][scol] = pkb;
  };
  auto packV = [&]() {
    const unsigned* au = (const unsigned*)&pva;
    const unsigned* bu = (const unsigned*)&pvb;
#pragma unroll
    for (int e = 0; e < 4; ++e) {
      // {lo16 = pva.short[2e] (key 2kp), hi16 = pvb.short[2e] (key 2kp+1)}
      sVt2[d0 + 2 * e][vcol]     = __builtin_amdgcn_perm(bu[e], au[e], 0x05040100u);
      sVt2[d0 + 2 * e + 1][vcol] = __builtin_amdgcn_perm(bu[e], au[e], 0x07060302u);
    }
  };

  // prologue: issue first tile's loads (regs only; LDS writes in first tile)
  loadK(kts);
  loadV(kts);

  auto tile = [&](int kt, auto mc) {
    constexpr bool MASK = decltype(mc)::value;
    const int k0 = kt * 64;
    __syncthreads();   // protect sK/sVt2 from previous tile's readers
    writeK();          // stage tile t (vmcnt wait: loads are one tile old)
    packV();
    if (kt + 1 < kte) {          // issue next tile's loads (regs)
      loadK(kt + 1);
      loadV(kt + 1);
    }
    __syncthreads();   // staged LDS visible to all waves

    // S^T = K Q^T : lane holds S[key=c*16+quad*4+r][q=l16]
    f32x4 sacc[4];
#pragma unroll
    for (int c = 0; c < 4; ++c) {
      f32x4 a = (f32x4){0.f, 0.f, 0.f, 0.f};
      a = __builtin_amdgcn_mfma_f32_16x16x32_bf16(
              *(const bf16x8*)&sK[c * 16 + l16][quad * 8], qf[0], a, 0, 0, 0);
      a = __builtin_amdgcn_mfma_f32_16x16x32_bf16(
              *(const bf16x8*)&sK[c * 16 + l16][32 + quad * 8], qf[1], a, 0, 0, 0);
      sacc[c] = a;
    }

    // softmax numerator in-lane: p = exp2(sacc*C1 + bias0[r] + bAdd[c])
    const float bAdd[4] = {0.f, bA1, bA2, bA3};
    float pv[4][4];
    int dq = 0;
    if constexpr (MASK) dq = qi - k0 - quad * 4;   // keep if c*16+r <= dq
#pragma unroll
    for (int c = 0; c < 4; ++c) {
#pragma unroll
      for (int r = 0; r < 4; ++r) {
        float p = EXP2F(fmaf(sacc[c][r], C1, bias0[r] + bAdd[c]));
        if constexpr (MASK) p = (c * 16 + r <= dq) ? p : 0.0f;
        pv[c][r] = p;
      }
      lsum += (pv[c][0] + pv[c][1]) + (pv[c][2] + pv[c][3]);
    }

    // O += P V : A-frag assembled in registers (2 swaps per 32-key half)
#pragma unroll
    for (int s = 0; s < 2; ++s) {
      unsigned X = cvt_pk_bf16(pv[2 * s][0],     pv[2 * s][1]);
      unsigned Y = cvt_pk_bf16(pv[2 * s][2],     pv[2 * s][3]);
      unsigned Z = cvt_pk_bf16(pv[2 * s + 1][0], pv[2 * s + 1][1]);
      unsigned W = cvt_pk_bf16(pv[2 * s + 1][2], pv[2 * s + 1][3]);
      permlane32_swap(X, Z);   // X=w0, Z=w1
      permlane32_swap(Y, W);   // Y=w2, W=w3
      bf16x8 pa;
      unsigned* pw = (unsigned*)&pa;
      pw[0] = X; pw[1] = Z; pw[2] = Y; pw[3] = W;
#pragma unroll
      for (int c = 0; c < 4; ++c) {
        const unsigned* vp = &sVt2[c * 16 + l16][s * 16 + quad * 4];
        bf16x4 vlo = *(const bf16x4*)vp;
        bf16x4 vhi = *(const bf16x4*)(vp + 2);
        bf16x8 vf = {vlo[0], vlo[1], vlo[2], vlo[3], vhi[0], vhi[1], vhi[2], vhi[3]};
        oacc[c] = __builtin_amdgcn_mfma_f32_16x16x32_bf16(pa, vf, oacc[c], 0, 0, 0);
      }
    }

#pragma unroll
    for (int r = 0; r < 4; ++r) bias0[r] += c64;   // k0 advances 64 next tile
  };

  // all tiles except the diagonal (last of the LAST chunk) are fully causal
  const int kfull = (kte == n) ? (kte - 1) : kte;
  for (int kt = kts; kt < kfull; ++kt) tile(kt, BoolT<false>{});
  if (kte == n) tile(n - 1, BoolT<true>{});   // diagonal tile: mask

  // epilogue: unnormalized O partial (bf16) + l partial (fp32)
  {
    // total l for query l16: reduce over the 4 quad lanes
    float lt = lsum;
    lt += __shfl_xor(lt, 16);
    lt += __shfl_xor(lt, 32);
    const int pidx = (b * NH + h) * NCHB + item;
    short* po = Po + (size_t)pidx * 4096;   // [64 rows][64 dims]
    float* pl = Pl + (size_t)pidx * 64;
#pragma unroll
    for (int r = 0; r < 4; ++r) {
      const int row = wv * 16 + quad * 4 + r;
      const float lr = __shfl(lt, quad * 4 + r, 16);  // l of query quad*4+r
      if (l16 == 0) pl[row] = lr;
#pragma unroll
      for (int c = 0; c < 4; ++c)
        po[row * 64 + c * 16 + l16] = f2bf(oacc[c][r]);
    }
  }
}

// ---------------------------------------------------------------------------
// Combine: O[row] = (sum_j Oj)/(sum_j lj) -> bf16, for ALL query tiles.
// 65536 (b,h,qt,row) rows x 64 dims; 32 rows/block, 8 threads/row.
// chunks per qt: (qt>>3)+1; slab base cum(qt) = (g+1)*(4g + (qt&7)), g=qt>>3.
// ---------------------------------------------------------------------------
__global__ __launch_bounds__(256) void combine(const short* __restrict__ Po,
                                               const float* __restrict__ Pl,
                                               short* __restrict__ O) {
  const int g = blockIdx.x * 32 + (threadIdx.x >> 3);   // 0..65535
  const int d = (threadIdx.x & 7) << 3;
  const int row = g & 63;
  const int qt  = (g >> 6) & 31;
  const int h   = (g >> 11) & 15;
  const int b   = g >> 15;
  const int gq  = qt >> 3;
  const int nch = gq + 1;
  const int cum = (gq + 1) * (4 * gq + (qt & 7));
  const int sbase = (b * NH + h) * NCHB + cum;

  float l = 0.f;
  float acc[8] = {0.f, 0.f, 0.f, 0.f, 0.f, 0.f, 0.f, 0.f};
  for (int jj = 0; jj < nch; ++jj) {
    l += Pl[(size_t)(sbase + jj) * 64 + row];
    const short* p = Po + (size_t)(sbase + jj) * 4096 + row * 64 + d;
    bf16x8 a = *(const bf16x8*)p;
#pragma unroll
    for (int e = 0; e < 8; ++e) acc[e] += bf2f(a[e]);
  }
  const float inv = 1.0f / fmaxf(l, 1e-37f);
  const int qi = qt * 64 + row;
  short* orow = O + (size_t)b * T_SEQ * DM + (size_t)qi * DM + h * HD + d;
  bf16x8 o;
#pragma unroll
  for (int e = 0; e < 8; ++e) o[e] = f2bf(acc[e] * inv);
  *(bf16x8*)orow = o;
}

// ---------------------------------------------------------------------------
extern "C" void kernel_launch(void* const* d_in, const int* in_sizes, int n_in,
                              void* d_out, int out_size, void* d_ws, size_t ws_size,
                              hipStream_t stream) {
  float* out = (float*)d_out;   // fp32 output

  short* ws = (short*)d_ws;
  const size_t plane = (size_t)NROW * DM;   // 4M elements
  const size_t wsz   = (size_t)DM * DM;     // 1M elements
  const size_t nslab = (size_t)32 * NCHB;   // 2560 partial slabs
  short* xb  = ws;
  short* Wqb = xb + plane;
  short* Wkb = Wqb + wsz;
  short* Wvb = Wkb + wsz;
  short* Wob = Wvb + wsz;
  short* Qb  = Wob + wsz;
  short* Kb  = Qb + plane;
  short* Vb  = Kb + plane;
  short* Ab  = Vb + plane;
  short* Po  = Ab + plane;                  // 2560 slabs * 4096 bf16 = 21 MB
  float* Pl  = (float*)(Po + nslab * 4096); // 2560 * 64 fp32 = 655 KB

  dim3 blk(256);
  convert_all<<<8192, blk, 0, stream>>>(
      (const float*)d_in[0], (const float*)d_in[1], (const float*)d_in[2],
      (const float*)d_in[3], (const float*)d_in[4],
      xb, Wqb, Wkb, Wvb, Wob);

  gemm_qkv<<<dim3(NROW / 128, DM / 128, 3), blk, 0, stream>>>(xb, Wqb, Wkb, Wvb, Qb, Kb, Vb);
  flash_alibi<<<dim3(NCHB, NH, 2), blk, 0, stream>>>(Qb, Kb, Vb, Ab, Po, Pl);
  combine<<<2048, blk, 0, stream>>>(Po, Pl, Ab);
  gemm_out<<<dim3(NROW / 64, DM / 128, 1), blk, 0, stream>>>(Ab, Wob, out);
}

// Round 11
// 170.556 us; speedup vs baseline: 1.8391x; 1.0524x over previous
//
#include <hip/hip_runtime.h>
#include <math.h>

// ALiBi attention: B=2, T=2048, D=1024, H=16, hd=64. fp32 in/out.
// Round 18: ALiBi distance-based tile skip. KV tile kt is dropped when even
// its closest (q,k) pair has bias < -40 in log2 units (keep iff qt-kt <= D,
// D = floor((40/sl2+63)/64)): skipped mass <= ~2^-34 of row mass -- far
// below bf16 resolution. 56.3% of flash tiles survive. Range-clamp only;
// round-17 flash body (verified, 44.3us) is otherwise byte-identical.
// GEMMs / convert / combine unchanged from round 17.

#define T_SEQ 2048
#define DM    1024
#define NH    16
#define HD    64
#define NROW  4096   // B*T
#define NCHB  80     // chunks per (h,b): qt/8 -> 1,2,3,4 chunks

typedef __attribute__((ext_vector_type(8))) short bf16x8;
typedef __attribute__((ext_vector_type(4))) short bf16x4;
typedef __attribute__((ext_vector_type(4))) float f32x4;

template <bool M> struct BoolT { static constexpr bool value = M; };

__device__ __forceinline__ short f2bf(float f) {
  unsigned u = __float_as_uint(f);
  u += 0x7FFFu + ((u >> 16) & 1u);
  return (short)(u >> 16);
}
__device__ __forceinline__ float bf2f(short s) {
  return __uint_as_float(((unsigned)(unsigned short)s) << 16);
}

// RNE pack of two f32 -> {lo16=bf16(a), hi16=bf16(b)} in one instruction.
__device__ __forceinline__ unsigned cvt_pk_bf16(float a, float b) {
  unsigned r;
  asm("v_cvt_pk_bf16_f32 %0, %1, %2" : "=v"(r) : "v"(a), "v"(b));
  return r;
}

// v_permlane32_swap_b32 a, b: a.hi32lanes <-> b.lo32lanes.
__device__ __forceinline__ void permlane32_swap(unsigned &a, unsigned &b) {
  asm("v_permlane32_swap_b32 %0, %1" : "+v"(a), "+v"(b));
}

#if __has_builtin(__builtin_amdgcn_exp2f)
#define EXP2F(x) __builtin_amdgcn_exp2f(x)
#else
#define EXP2F(x) exp2f(x)
#endif

// async global->LDS, 16B per lane; lds dest is wave-uniform base + lane*16B.
__device__ __forceinline__ void gload_lds16(short* lds, const short* g) {
  __builtin_amdgcn_global_load_lds((const __attribute__((address_space(1))) void*)g,
                                   (__attribute__((address_space(3))) void*)lds, 16, 0, 0);
}

// ---------------------------------------------------------------------------
// Merged fp32->bf16 conversion: x (4M) + 4 weights (1M each), 2M float4 groups.
// ---------------------------------------------------------------------------
__global__ __launch_bounds__(256) void convert_all(
    const float* __restrict__ x,  const float* __restrict__ wq,
    const float* __restrict__ wk, const float* __restrict__ wv,
    const float* __restrict__ wo,
    short* __restrict__ xb,  short* __restrict__ wqb, short* __restrict__ wkb,
    short* __restrict__ wvb, short* __restrict__ wob) {
  const int i = blockIdx.x * 256 + threadIdx.x;
  const float* s; short* d; int off;
  if (i < (1 << 20)) { s = x; d = xb; off = i; }
  else {
    const int j = i - (1 << 20);
    const int w = j >> 18;
    off = j & ((1 << 18) - 1);
    s = (w == 0) ? wq : (w == 1) ? wk : (w == 2) ? wv : wo;
    d = (w == 0) ? wqb : (w == 1) ? wkb : (w == 2) ? wvb : wob;
  }
  const float4 v = ((const float4*)s)[off];
  bf16x4 o = {f2bf(v.x), f2bf(v.y), f2bf(v.z), f2bf(v.w)};
  *(bf16x4*)(d + 4 * (size_t)off) = o;
}

// ---------------------------------------------------------------------------
// GEMM 128x128, BK=32 (round-5/14 verified): C[m][n] = sum_k A[m][k]*W[n][k].
// ---------------------------------------------------------------------------
template <typename OutT>
__device__ __forceinline__ void gemm_body(const short* __restrict__ A,
                                          const short* __restrict__ W,
                                          OutT* __restrict__ C) {
  __shared__ short sA[128][32];
  __shared__ short sB[128][32];
  const int tid  = threadIdx.x;
  const int lane = tid & 63, wv = tid >> 6;
  const int quad = lane >> 4, l16 = lane & 15;
  const int wm = (wv >> 1) * 64, wn = (wv & 1) * 64;
  const size_t m0 = (size_t)blockIdx.x * 128, n0 = (size_t)blockIdx.y * 128;

  f32x4 acc[4][4];
#pragma unroll
  for (int i = 0; i < 4; ++i)
#pragma unroll
    for (int j = 0; j < 4; ++j) acc[i][j] = (f32x4){0.f, 0.f, 0.f, 0.f};

  const int grow = lane >> 2;
  const int gcol = (lane & 3) << 3;

  for (int k0 = 0; k0 < DM; k0 += 32) {
    __syncthreads();
    {
      const short* ga = A + (m0 + wv * 32 + grow) * DM + k0 + gcol;
      gload_lds16(&sA[wv * 32][0],      ga);
      gload_lds16(&sA[wv * 32 + 16][0], ga + 16 * DM);
      const short* gb = W + (n0 + wv * 32 + grow) * DM + k0 + gcol;
      gload_lds16(&sB[wv * 32][0],      gb);
      gload_lds16(&sB[wv * 32 + 16][0], gb + 16 * DM);
    }
    __syncthreads();

    bf16x8 af[4], bfr[4];
#pragma unroll
    for (int t = 0; t < 4; ++t) {
      af[t]  = *(const bf16x8*)&sA[wm + t * 16 + l16][quad * 8];
      bfr[t] = *(const bf16x8*)&sB[wn + t * 16 + l16][quad * 8];
    }
#pragma unroll
    for (int mt = 0; mt < 4; ++mt)
#pragma unroll
      for (int nt = 0; nt < 4; ++nt)
        acc[mt][nt] = __builtin_amdgcn_mfma_f32_16x16x32_bf16(af[mt], bfr[nt], acc[mt][nt], 0, 0, 0);
  }
#pragma unroll
  for (int mt = 0; mt < 4; ++mt) {
#pragma unroll
    for (int r = 0; r < 4; ++r) {
      const size_t m = m0 + wm + mt * 16 + quad * 4 + r;
      OutT* crow = C + m * DM;
#pragma unroll
      for (int nt = 0; nt < 4; ++nt) {
        const float v = acc[mt][nt][r];
        if constexpr (sizeof(OutT) == 2)
          crow[n0 + wn + nt * 16 + l16] = f2bf(v);
        else
          crow[n0 + wn + nt * 16 + l16] = v;
      }
    }
  }
}

__global__ __launch_bounds__(256) void gemm_qkv(
    const short* __restrict__ x,
    const short* __restrict__ Wq, const short* __restrict__ Wk, const short* __restrict__ Wv,
    short* __restrict__ Qb, short* __restrict__ Kb, short* __restrict__ Vb) {
  const short* W = (blockIdx.z == 0) ? Wq : (blockIdx.z == 1) ? Wk : Wv;
  short*       C = (blockIdx.z == 0) ? Qb : (blockIdx.z == 1) ? Kb : Vb;
  gemm_body<short>(x, W, C);
}

// ---------------------------------------------------------------------------
// Output GEMM: 64x128 tile (round-14 verified; fixes 1-block/CU cliff).
// ---------------------------------------------------------------------------
__global__ __launch_bounds__(256) void gemm_out(const short* __restrict__ A,
                                                const short* __restrict__ W,
                                                float* __restrict__ C) {
  __shared__ short sA[64][32];
  __shared__ short sB[128][32];
  const int tid  = threadIdx.x;
  const int lane = tid & 63, wv = tid >> 6;
  const int quad = lane >> 4, l16 = lane & 15;
  const int wm = (wv >> 1) * 32, wn = (wv & 1) * 64;
  const size_t m0 = (size_t)blockIdx.x * 64, n0 = (size_t)blockIdx.y * 128;

  f32x4 acc[2][4];
#pragma unroll
  for (int i = 0; i < 2; ++i)
#pragma unroll
    for (int j = 0; j < 4; ++j) acc[i][j] = (f32x4){0.f, 0.f, 0.f, 0.f};

  const int grow = lane >> 2;
  const int gcol = (lane & 3) << 3;

  for (int k0 = 0; k0 < DM; k0 += 32) {
    __syncthreads();
#pragma unroll
    for (int cc = 0; cc < 3; ++cc) {
      const int i = wv * 3 + cc;   // 0..11, wave-uniform per call
      short* dst = (i < 4) ? &sA[i * 16][0] : &sB[(i - 4) * 16][0];
      const short* src = (i < 4)
          ? A + (m0 + i * 16 + grow) * DM + k0 + gcol
          : W + (n0 + (i - 4) * 16 + grow) * DM + k0 + gcol;
      gload_lds16(dst, src);
    }
    __syncthreads();

    bf16x8 af[2], bfr[4];
#pragma unroll
    for (int t = 0; t < 2; ++t)
      af[t] = *(const bf16x8*)&sA[wm + t * 16 + l16][quad * 8];
#pragma unroll
    for (int t = 0; t < 4; ++t)
      bfr[t] = *(const bf16x8*)&sB[wn + t * 16 + l16][quad * 8];
#pragma unroll
    for (int mt = 0; mt < 2; ++mt)
#pragma unroll
      for (int nt = 0; nt < 4; ++nt)
        acc[mt][nt] = __builtin_amdgcn_mfma_f32_16x16x32_bf16(af[mt], bfr[nt], acc[mt][nt], 0, 0, 0);
  }
#pragma unroll
  for (int mt = 0; mt < 2; ++mt) {
#pragma unroll
    for (int r = 0; r < 4; ++r) {
      const size_t m = m0 + wm + mt * 16 + quad * 4 + r;
      float* crow = C + m * DM;
#pragma unroll
      for (int nt = 0; nt < 4; ++nt)
        crow[n0 + wn + nt * 16 + l16] = acc[mt][nt][r];
    }
  }
}

// ---------------------------------------------------------------------------
// Flash attention, ALiBi, causal — uniform-chunk mapping, swapped QK^T,
// ALiBi distance skip. blockIdx.x = item in [0,80): chunk j of qt,
// KV tiles [max(j*8, qt-D), min(j*8+8, qt+1)).
// Per-tile schedule (verified): barrier1 -> ds_write K/V (loads one tile
// old) -> issue loads t+1 -> barrier2 -> compute.
// S^T = mfma(K,Q); softmax in-lane; PV A-frag via cvt_pk + permlane32_swap;
// sVt2 column permutation col(p)=(p&3)*2+((p>>2)&1)+(p&~7).
// Fully-skipped chunks write l=0/O=0 partials (combine sums them; the
// diagonal chunk is always kept so every row has l > 0).
// ---------------------------------------------------------------------------
__global__ __launch_bounds__(256) void flash_alibi(const short* __restrict__ Q,
                                                   const short* __restrict__ K,
                                                   const short* __restrict__ V,
                                                   short* __restrict__ O,
                                                   short* __restrict__ Po,
                                                   float* __restrict__ Pl) {
  __shared__ short sK[64][72];             // [key][dim], padded
  __shared__ unsigned int sVt2[64][34];    // [dim][keypair-permuted]

  const int tid  = threadIdx.x;
  const int lane = tid & 63, wv = tid >> 6;
  const int quad = lane >> 4, l16 = lane & 15;
  const int item = blockIdx.x;

  int qt, j;
  if (item < 8)       { qt = item;                j = 0; }
  else if (item < 24) { qt = 8 + (item - 8) / 2;  j = (item - 8) % 2; }
  else if (item < 48) { qt = 16 + (item - 24) / 3; j = (item - 24) % 3; }
  else                { qt = 24 + (item - 48) / 4; j = (item - 48) % 4; }

  const int n   = qt + 1;
  const int kts = j * 8;
  const int kte = (kts + 8 < n) ? (kts + 8) : n;

  const int h = blockIdx.y, b = blockIdx.z;
  const size_t base = (size_t)b * T_SEQ * DM + (size_t)h * HD;
  const int qi_base = qt * 64;

  // Q fragments (identical layout serves as B-operand: col=l16, k=quad*8+j)
  bf16x8 qf[2];
  {
    const int qrow = qi_base + wv * 16 + l16;
    const short* qp = Q + base + (size_t)qrow * DM + quad * 8;
    qf[0] = *(const bf16x8*)(qp);
    qf[1] = *(const bf16x8*)(qp + 32);
  }

  const float slope = exp2f(-0.5f * (float)(h + 1));
  const float sl2   = slope * 1.4426950408889634f;     // slope * log2(e)
  const float C1    = 0.18033688011112042f;            // 0.125 * log2(e)
  const float bA1 = 16.f * sl2, bA2 = 32.f * sl2, bA3 = 48.f * sl2;
  const float c64 = 64.f * sl2;

  // ALiBi skip: keep tile iff qt-kt <= D, D = floor((40/sl2 + 63)/64).
  // Skipped tiles have min-distance bias < -40 (log2) -> mass < ~2^-34 of
  // the row max; invisible at bf16 precision.
  const int D = (int)((40.0f / sl2 + 63.0f) * 0.015625f);
  const int kmin = qt - D;
  const int kts2 = (kts > kmin) ? kts : kmin;

  const int srow = tid >> 3;          // K staging row (0..31)
  const int scol = (tid & 7) << 3;    // K staging col
  const int kp   = tid >> 3;          // V staging key pair (0..31)
  const int d0   = (tid & 7) << 3;    // V staging dim group
  // PV key-order permutation: physical pair p stored at column col(p).
  const int vcol = ((kp & 3) << 1) + ((kp >> 2) & 1) + (kp & ~7);

  f32x4 oacc[4];
#pragma unroll
  for (int c = 0; c < 4; ++c) oacc[c] = (f32x4){0.f, 0.f, 0.f, 0.f};
  float lsum = 0.f;                   // partial row-sum for query l16

  const int qi = qi_base + wv * 16 + l16;   // this lane's query row
  // bias0[r] = -sl2*(qi - kj) - 12*log2(e) at kj = kts2*64 + quad*4 + r
  float bias0[4];
#pragma unroll
  for (int r = 0; r < 4; ++r)
    bias0[r] = sl2 * (float)(kts2 * 64 + quad * 4 + r - qi) - 17.312340490667562f;

  // staged tile registers: loaded one tile EARLY, written to LDS in the
  // protected staging slot (between the two barriers).
  bf16x8 pka, pkb, pva, pvb;
  auto loadK = [&](int kt) {
    const short* g0 = K + base + (size_t)(kt * 64 + srow) * DM + scol;
    pka = *(const bf16x8*)g0;
    pkb = *(const bf16x8*)(g0 + 32 * DM);
  };
  auto loadV = [&](int kt) {
    const short* v0 = V + base + (size_t)(kt * 64 + 2 * kp) * DM + d0;
    pva = *(const bf16x8*)v0;
    pvb = *(const bf16x8*)(v0 + DM);
  };
  auto writeK = [&]() {
    *(bf16x8*)&sK[srow][scol]      = pka;
    *(bf16x8*)&sK[srow + 32][scol] = pkb;
  };
  auto packV = [&]() {
    const unsigned* au = (const unsigned*)&pva;
    const unsigned* bu = (const unsigned*)&pvb;
#pragma unroll
    for (int e = 0; e < 4; ++e) {
      // {lo16 = pva.short[2e] (key 2kp), hi16 = pvb.short[2e] (key 2kp+1)}
      sVt2[d0 + 2 * e][vcol]     = __builtin_amdgcn_perm(bu[e], au[e], 0x05040100u);
      sVt2[d0 + 2 * e + 1][vcol] = __builtin_amdgcn_perm(bu[e], au[e], 0x07060302u);
    }
  };

  auto tile = [&](int kt, auto mc) {
    constexpr bool MASK = decltype(mc)::value;
    const int k0 = kt * 64;
    __syncthreads();   // protect sK/sVt2 from previous tile's readers
    writeK();          // stage tile t (vmcnt wait: loads are one tile old)
    packV();
    if (kt + 1 < kte) {          // issue next tile's loads (regs)
      loadK(kt + 1);
      loadV(kt + 1);
    }
    __syncthreads();   // staged LDS visible to all waves

    // S^T = K Q^T : lane holds S[key=c*16+quad*4+r][q=l16]
    f32x4 sacc[4];
#pragma unroll
    for (int c = 0; c < 4; ++c) {
      f32x4 a = (f32x4){0.f, 0.f, 0.f, 0.f};
      a = __builtin_amdgcn_mfma_f32_16x16x32_bf16(
              *(const bf16x8*)&sK[c * 16 + l16][quad * 8], qf[0], a, 0, 0, 0);
      a = __builtin_amdgcn_mfma_f32_16x16x32_bf16(
              *(const bf16x8*)&sK[c * 16 + l16][32 + quad * 8], qf[1], a, 0, 0, 0);
      sacc[c] = a;
    }

    // softmax numerator in-lane: p = exp2(sacc*C1 + bias0[r] + bAdd[c])
    const float bAdd[4] = {0.f, bA1, bA2, bA3};
    float pv[4][4];
    int dq = 0;
    if constexpr (MASK) dq = qi - k0 - quad * 4;   // keep if c*16+r <= dq
#pragma unroll
    for (int c = 0; c < 4; ++c) {
#pragma unroll
      for (int r = 0; r < 4; ++r) {
        float p = EXP2F(fmaf(sacc[c][r], C1, bias0[r] + bAdd[c]));
        if constexpr (MASK) p = (c * 16 + r <= dq) ? p : 0.0f;
        pv[c][r] = p;
      }
      lsum += (pv[c][0] + pv[c][1]) + (pv[c][2] + pv[c][3]);
    }

    // O += P V : A-frag assembled in registers (2 swaps per 32-key half)
#pragma unroll
    for (int s = 0; s < 2; ++s) {
      unsigned X = cvt_pk_bf16(pv[2 * s][0],     pv[2 * s][1]);
      unsigned Y = cvt_pk_bf16(pv[2 * s][2],     pv[2 * s][3]);
      unsigned Z = cvt_pk_bf16(pv[2 * s + 1][0], pv[2 * s + 1][1]);
      unsigned W = cvt_pk_bf16(pv[2 * s + 1][2], pv[2 * s + 1][3]);
      permlane32_swap(X, Z);   // X=w0, Z=w1
      permlane32_swap(Y, W);   // Y=w2, W=w3
      bf16x8 pa;
      unsigned* pw = (unsigned*)&pa;
      pw[0] = X; pw[1] = Z; pw[2] = Y; pw[3] = W;
#pragma unroll
      for (int c = 0; c < 4; ++c) {
        const unsigned* vp = &sVt2[c * 16 + l16][s * 16 + quad * 4];
        bf16x4 vlo = *(const bf16x4*)vp;
        bf16x4 vhi = *(const bf16x4*)(vp + 2);
        bf16x8 vf = {vlo[0], vlo[1], vlo[2], vlo[3], vhi[0], vhi[1], vhi[2], vhi[3]};
        oacc[c] = __builtin_amdgcn_mfma_f32_16x16x32_bf16(pa, vf, oacc[c], 0, 0, 0);
      }
    }

#pragma unroll
    for (int r = 0; r < 4; ++r) bias0[r] += c64;   // k0 advances 64 next tile
  };

  if (kts2 < kte) {
    // prologue: issue first tile's loads (regs only; LDS writes in tile 0)
    loadK(kts2);
    loadV(kts2);
    // all tiles except the diagonal (last of the LAST chunk) are fully causal
    const int kfull = (kte == n) ? (kte - 1) : kte;
    for (int kt = kts2; kt < kfull; ++kt) tile(kt, BoolT<false>{});
    if (kte == n) tile(n - 1, BoolT<true>{});   // diagonal tile: mask
  }
  // else: fully-skipped chunk -> zero partials below

  // epilogue: unnormalized O partial (bf16) + l partial (fp32)
  {
    // total l for query l16: reduce over the 4 quad lanes
    float lt = lsum;
    lt += __shfl_xor(lt, 16);
    lt += __shfl_xor(lt, 32);
    const int pidx = (b * NH + h) * NCHB + item;
    short* po = Po + (size_t)pidx * 4096;   // [64 rows][64 dims]
    float* pl = Pl + (size_t)pidx * 64;
#pragma unroll
    for (int r = 0; r < 4; ++r) {
      const int row = wv * 16 + quad * 4 + r;
      const float lr = __shfl(lt, quad * 4 + r, 16);  // l of query quad*4+r
      if (l16 == 0) pl[row] = lr;
#pragma unroll
      for (int c = 0; c < 4; ++c)
        po[row * 64 + c * 16 + l16] = f2bf(oacc[c][r]);
    }
  }
}

// ---------------------------------------------------------------------------
// Combine: O[row] = (sum_j Oj)/(sum_j lj) -> bf16, for ALL query tiles.
// 65536 (b,h,qt,row) rows x 64 dims; 32 rows/block, 8 threads/row.
// chunks per qt: (qt>>3)+1; slab base cum(qt) = (g+1)*(4g + (qt&7)), g=qt>>3.
// ---------------------------------------------------------------------------
__global__ __launch_bounds__(256) void combine(const short* __restrict__ Po,
                                               const float* __restrict__ Pl,
                                               short* __restrict__ O) {
  const int g = blockIdx.x * 32 + (threadIdx.x >> 3);   // 0..65535
  const int d = (threadIdx.x & 7) << 3;
  const int row = g & 63;
  const int qt  = (g >> 6) & 31;
  const int h   = (g >> 11) & 15;
  const int b   = g >> 15;
  const int gq  = qt >> 3;
  const int nch = gq + 1;
  const int cum = (gq + 1) * (4 * gq + (qt & 7));
  const int sbase = (b * NH + h) * NCHB + cum;

  float l = 0.f;
  float acc[8] = {0.f, 0.f, 0.f, 0.f, 0.f, 0.f, 0.f, 0.f};
  for (int jj = 0; jj < nch; ++jj) {
    l += Pl[(size_t)(sbase + jj) * 64 + row];
    const short* p = Po + (size_t)(sbase + jj) * 4096 + row * 64 + d;
    bf16x8 a = *(const bf16x8*)p;
#pragma unroll
    for (int e = 0; e < 8; ++e) acc[e] += bf2f(a[e]);
  }
  const float inv = 1.0f / fmaxf(l, 1e-37f);
  const int qi = qt * 64 + row;
  short* orow = O + (size_t)b * T_SEQ * DM + (size_t)qi * DM + h * HD + d;
  bf16x8 o;
#pragma unroll
  for (int e = 0; e < 8; ++e) o[e] = f2bf(acc[e] * inv);
  *(bf16x8*)orow = o;
}

// ---------------------------------------------------------------------------
extern "C" void kernel_launch(void* const* d_in, const int* in_sizes, int n_in,
                              void* d_out, int out_size, void* d_ws, size_t ws_size,
                              hipStream_t stream) {
  float* out = (float*)d_out;   // fp32 output

  short* ws = (short*)d_ws;
  const size_t plane = (size_t)NROW * DM;   // 4M elements
  const size_t wsz   = (size_t)DM * DM;     // 1M elements
  const size_t nslab = (size_t)32 * NCHB;   // 2560 partial slabs
  short* xb  = ws;
  short* Wqb = xb + plane;
  short* Wkb = Wqb + wsz;
  short* Wvb = Wkb + wsz;
  short* Wob = Wvb + wsz;
  short* Qb  = Wob + wsz;
  short* Kb  = Qb + plane;
  short* Vb  = Kb + plane;
  short* Ab  = Vb + plane;
  short* Po  = Ab + plane;                  // 2560 slabs * 4096 bf16 = 21 MB
  float* Pl  = (float*)(Po + nslab * 4096); // 2560 * 64 fp32 = 655 KB

  dim3 blk(256);
  convert_all<<<8192, blk, 0, stream>>>(
      (const float*)d_in[0], (const float*)d_in[1], (const float*)d_in[2],
      (const float*)d_in[3], (const float*)d_in[4],
      xb, Wqb, Wkb, Wvb, Wob);

  gemm_qkv<<<dim3(NROW / 128, DM / 128, 3), blk, 0, stream>>>(xb, Wqb, Wkb, Wvb, Qb, Kb, Vb);
  flash_alibi<<<dim3(NCHB, NH, 2), blk, 0, stream>>>(Qb, Kb, Vb, Ab, Po, Pl);
  combine<<<2048, blk, 0, stream>>>(Po, Pl, Ab);
  gemm_out<<<dim3(NROW / 64, DM / 128, 1), blk, 0, stream>>>(Ab, Wob, out);
}

// Round 12
// 168.812 us; speedup vs baseline: 1.8581x; 1.0103x over previous
//
#include <hip/hip_runtime.h>
#include <math.h>

// ALiBi attention: B=2, T=2048, D=1024, H=16, hd=64. fp32 in/out.
// Round 19: gemm_qkv BK=32 -> BK=64 (16 K-iterations, half the barrier
// drains). LDS kept as two [128][32] half-buffers per operand (row stride
// 64B = the verified bank-safe layout; a [128][64] stride would be a
// 16-way b128 read conflict per G4). Staging bytes/instructions unchanged.
// Flash (round-18 verified, ALiBi skip) / gemm_out / convert / combine
// byte-identical to round 18.

#define T_SEQ 2048
#define DM    1024
#define NH    16
#define HD    64
#define NROW  4096   // B*T
#define NCHB  80     // chunks per (h,b): qt/8 -> 1,2,3,4 chunks

typedef __attribute__((ext_vector_type(8))) short bf16x8;
typedef __attribute__((ext_vector_type(4))) short bf16x4;
typedef __attribute__((ext_vector_type(4))) float f32x4;

template <bool M> struct BoolT { static constexpr bool value = M; };

__device__ __forceinline__ short f2bf(float f) {
  unsigned u = __float_as_uint(f);
  u += 0x7FFFu + ((u >> 16) & 1u);
  return (short)(u >> 16);
}
__device__ __forceinline__ float bf2f(short s) {
  return __uint_as_float(((unsigned)(unsigned short)s) << 16);
}

// RNE pack of two f32 -> {lo16=bf16(a), hi16=bf16(b)} in one instruction.
__device__ __forceinline__ unsigned cvt_pk_bf16(float a, float b) {
  unsigned r;
  asm("v_cvt_pk_bf16_f32 %0, %1, %2" : "=v"(r) : "v"(a), "v"(b));
  return r;
}

// v_permlane32_swap_b32 a, b: a.hi32lanes <-> b.lo32lanes.
__device__ __forceinline__ void permlane32_swap(unsigned &a, unsigned &b) {
  asm("v_permlane32_swap_b32 %0, %1" : "+v"(a), "+v"(b));
}

#if __has_builtin(__builtin_amdgcn_exp2f)
#define EXP2F(x) __builtin_amdgcn_exp2f(x)
#else
#define EXP2F(x) exp2f(x)
#endif

// async global->LDS, 16B per lane; lds dest is wave-uniform base + lane*16B.
__device__ __forceinline__ void gload_lds16(short* lds, const short* g) {
  __builtin_amdgcn_global_load_lds((const __attribute__((address_space(1))) void*)g,
                                   (__attribute__((address_space(3))) void*)lds, 16, 0, 0);
}

// ---------------------------------------------------------------------------
// Merged fp32->bf16 conversion: x (4M) + 4 weights (1M each), 2M float4 groups.
// ---------------------------------------------------------------------------
__global__ __launch_bounds__(256) void convert_all(
    const float* __restrict__ x,  const float* __restrict__ wq,
    const float* __restrict__ wk, const float* __restrict__ wv,
    const float* __restrict__ wo,
    short* __restrict__ xb,  short* __restrict__ wqb, short* __restrict__ wkb,
    short* __restrict__ wvb, short* __restrict__ wob) {
  const int i = blockIdx.x * 256 + threadIdx.x;
  const float* s; short* d; int off;
  if (i < (1 << 20)) { s = x; d = xb; off = i; }
  else {
    const int j = i - (1 << 20);
    const int w = j >> 18;
    off = j & ((1 << 18) - 1);
    s = (w == 0) ? wq : (w == 1) ? wk : (w == 2) ? wv : wo;
    d = (w == 0) ? wqb : (w == 1) ? wkb : (w == 2) ? wvb : wob;
  }
  const float4 v = ((const float4*)s)[off];
  bf16x4 o = {f2bf(v.x), f2bf(v.y), f2bf(v.z), f2bf(v.w)};
  *(bf16x4*)(d + 4 * (size_t)off) = o;
}

// ---------------------------------------------------------------------------
// GEMM 128x128, BK=64 (two verified [128][32] half-buffers per operand):
// C[m][n] = sum_k A[m][k]*W[n][k]. 16 K-iterations, 2 barriers each.
// ---------------------------------------------------------------------------
template <typename OutT>
__device__ __forceinline__ void gemm_bk64_body(const short* __restrict__ A,
                                               const short* __restrict__ W,
                                               OutT* __restrict__ C) {
  __shared__ short sA0[128][32];
  __shared__ short sA1[128][32];
  __shared__ short sB0[128][32];
  __shared__ short sB1[128][32];
  const int tid  = threadIdx.x;
  const int lane = tid & 63, wv = tid >> 6;
  const int quad = lane >> 4, l16 = lane & 15;
  const int wm = (wv >> 1) * 64, wn = (wv & 1) * 64;
  const size_t m0 = (size_t)blockIdx.x * 128, n0 = (size_t)blockIdx.y * 128;

  f32x4 acc[4][4];
#pragma unroll
  for (int i = 0; i < 4; ++i)
#pragma unroll
    for (int j = 0; j < 4; ++j) acc[i][j] = (f32x4){0.f, 0.f, 0.f, 0.f};

  const int grow = lane >> 2;          // 0..15
  const int gcol = (lane & 3) << 3;    // 0..24 shorts (within 32-col half)

  for (int k0 = 0; k0 < DM; k0 += 64) {
    __syncthreads();
    {
      const short* ga = A + (m0 + wv * 32 + grow) * DM + k0 + gcol;
      gload_lds16(&sA0[wv * 32][0],      ga);
      gload_lds16(&sA0[wv * 32 + 16][0], ga + 16 * DM);
      gload_lds16(&sA1[wv * 32][0],      ga + 32);
      gload_lds16(&sA1[wv * 32 + 16][0], ga + 16 * DM + 32);
      const short* gb = W + (n0 + wv * 32 + grow) * DM + k0 + gcol;
      gload_lds16(&sB0[wv * 32][0],      gb);
      gload_lds16(&sB0[wv * 32 + 16][0], gb + 16 * DM);
      gload_lds16(&sB1[wv * 32][0],      gb + 32);
      gload_lds16(&sB1[wv * 32 + 16][0], gb + 16 * DM + 32);
    }
    __syncthreads();

    {
      bf16x8 af[4], bfr[4];
#pragma unroll
      for (int t = 0; t < 4; ++t) {
        af[t]  = *(const bf16x8*)&sA0[wm + t * 16 + l16][quad * 8];
        bfr[t] = *(const bf16x8*)&sB0[wn + t * 16 + l16][quad * 8];
      }
#pragma unroll
      for (int mt = 0; mt < 4; ++mt)
#pragma unroll
        for (int nt = 0; nt < 4; ++nt)
          acc[mt][nt] = __builtin_amdgcn_mfma_f32_16x16x32_bf16(af[mt], bfr[nt], acc[mt][nt], 0, 0, 0);
    }
    {
      bf16x8 af[4], bfr[4];
#pragma unroll
      for (int t = 0; t < 4; ++t) {
        af[t]  = *(const bf16x8*)&sA1[wm + t * 16 + l16][quad * 8];
        bfr[t] = *(const bf16x8*)&sB1[wn + t * 16 + l16][quad * 8];
      }
#pragma unroll
      for (int mt = 0; mt < 4; ++mt)
#pragma unroll
        for (int nt = 0; nt < 4; ++nt)
          acc[mt][nt] = __builtin_amdgcn_mfma_f32_16x16x32_bf16(af[mt], bfr[nt], acc[mt][nt], 0, 0, 0);
    }
  }
#pragma unroll
  for (int mt = 0; mt < 4; ++mt) {
#pragma unroll
    for (int r = 0; r < 4; ++r) {
      const size_t m = m0 + wm + mt * 16 + quad * 4 + r;
      OutT* crow = C + m * DM;
#pragma unroll
      for (int nt = 0; nt < 4; ++nt) {
        const float v = acc[mt][nt][r];
        if constexpr (sizeof(OutT) == 2)
          crow[n0 + wn + nt * 16 + l16] = f2bf(v);
        else
          crow[n0 + wn + nt * 16 + l16] = v;
      }
    }
  }
}

__global__ __launch_bounds__(256) void gemm_qkv(
    const short* __restrict__ x,
    const short* __restrict__ Wq, const short* __restrict__ Wk, const short* __restrict__ Wv,
    short* __restrict__ Qb, short* __restrict__ Kb, short* __restrict__ Vb) {
  const short* W = (blockIdx.z == 0) ? Wq : (blockIdx.z == 1) ? Wk : Wv;
  short*       C = (blockIdx.z == 0) ? Qb : (blockIdx.z == 1) ? Kb : Vb;
  gemm_bk64_body<short>(x, W, C);
}

// ---------------------------------------------------------------------------
// Output GEMM: 64x128 tile (round-14 verified; fixes 1-block/CU cliff).
// ---------------------------------------------------------------------------
__global__ __launch_bounds__(256) void gemm_out(const short* __restrict__ A,
                                                const short* __restrict__ W,
                                                float* __restrict__ C) {
  __shared__ short sA[64][32];
  __shared__ short sB[128][32];
  const int tid  = threadIdx.x;
  const int lane = tid & 63, wv = tid >> 6;
  const int quad = lane >> 4, l16 = lane & 15;
  const int wm = (wv >> 1) * 32, wn = (wv & 1) * 64;
  const size_t m0 = (size_t)blockIdx.x * 64, n0 = (size_t)blockIdx.y * 128;

  f32x4 acc[2][4];
#pragma unroll
  for (int i = 0; i < 2; ++i)
#pragma unroll
    for (int j = 0; j < 4; ++j) acc[i][j] = (f32x4){0.f, 0.f, 0.f, 0.f};

  const int grow = lane >> 2;
  const int gcol = (lane & 3) << 3;

  for (int k0 = 0; k0 < DM; k0 += 32) {
    __syncthreads();
#pragma unroll
    for (int cc = 0; cc < 3; ++cc) {
      const int i = wv * 3 + cc;   // 0..11, wave-uniform per call
      short* dst = (i < 4) ? &sA[i * 16][0] : &sB[(i - 4) * 16][0];
      const short* src = (i < 4)
          ? A + (m0 + i * 16 + grow) * DM + k0 + gcol
          : W + (n0 + (i - 4) * 16 + grow) * DM + k0 + gcol;
      gload_lds16(dst, src);
    }
    __syncthreads();

    bf16x8 af[2], bfr[4];
#pragma unroll
    for (int t = 0; t < 2; ++t)
      af[t] = *(const bf16x8*)&sA[wm + t * 16 + l16][quad * 8];
#pragma unroll
    for (int t = 0; t < 4; ++t)
      bfr[t] = *(const bf16x8*)&sB[wn + t * 16 + l16][quad * 8];
#pragma unroll
    for (int mt = 0; mt < 2; ++mt)
#pragma unroll
      for (int nt = 0; nt < 4; ++nt)
        acc[mt][nt] = __builtin_amdgcn_mfma_f32_16x16x32_bf16(af[mt], bfr[nt], acc[mt][nt], 0, 0, 0);
  }
#pragma unroll
  for (int mt = 0; mt < 2; ++mt) {
#pragma unroll
    for (int r = 0; r < 4; ++r) {
      const size_t m = m0 + wm + mt * 16 + quad * 4 + r;
      float* crow = C + m * DM;
#pragma unroll
      for (int nt = 0; nt < 4; ++nt)
        crow[n0 + wn + nt * 16 + l16] = acc[mt][nt][r];
    }
  }
}

// ---------------------------------------------------------------------------
// Flash attention, ALiBi, causal — uniform-chunk mapping, swapped QK^T,
// ALiBi distance skip (round-18 verified).
// ---------------------------------------------------------------------------
__global__ __launch_bounds__(256) void flash_alibi(const short* __restrict__ Q,
                                                   const short* __restrict__ K,
                                                   const short* __restrict__ V,
                                                   short* __restrict__ O,
                                                   short* __restrict__ Po,
                                                   float* __restrict__ Pl) {
  __shared__ short sK[64][72];             // [key][dim], padded
  __shared__ unsigned int sVt2[64][34];    // [dim][keypair-permuted]

  const int tid  = threadIdx.x;
  const int lane = tid & 63, wv = tid >> 6;
  const int quad = lane >> 4, l16 = lane & 15;
  const int item = blockIdx.x;

  int qt, j;
  if (item < 8)       { qt = item;                j = 0; }
  else if (item < 24) { qt = 8 + (item - 8) / 2;  j = (item - 8) % 2; }
  else if (item < 48) { qt = 16 + (item - 24) / 3; j = (item - 24) % 3; }
  else                { qt = 24 + (item - 48) / 4; j = (item - 48) % 4; }

  const int n   = qt + 1;
  const int kts = j * 8;
  const int kte = (kts + 8 < n) ? (kts + 8) : n;

  const int h = blockIdx.y, b = blockIdx.z;
  const size_t base = (size_t)b * T_SEQ * DM + (size_t)h * HD;
  const int qi_base = qt * 64;

  // Q fragments (identical layout serves as B-operand: col=l16, k=quad*8+j)
  bf16x8 qf[2];
  {
    const int qrow = qi_base + wv * 16 + l16;
    const short* qp = Q + base + (size_t)qrow * DM + quad * 8;
    qf[0] = *(const bf16x8*)(qp);
    qf[1] = *(const bf16x8*)(qp + 32);
  }

  const float slope = exp2f(-0.5f * (float)(h + 1));
  const float sl2   = slope * 1.4426950408889634f;     // slope * log2(e)
  const float C1    = 0.18033688011112042f;            // 0.125 * log2(e)
  const float bA1 = 16.f * sl2, bA2 = 32.f * sl2, bA3 = 48.f * sl2;
  const float c64 = 64.f * sl2;

  // ALiBi skip: keep tile iff qt-kt <= D, D = floor((40/sl2 + 63)/64).
  const int D = (int)((40.0f / sl2 + 63.0f) * 0.015625f);
  const int kmin = qt - D;
  const int kts2 = (kts > kmin) ? kts : kmin;

  const int srow = tid >> 3;          // K staging row (0..31)
  const int scol = (tid & 7) << 3;    // K staging col
  const int kp   = tid >> 3;          // V staging key pair (0..31)
  const int d0   = (tid & 7) << 3;    // V staging dim group
  // PV key-order permutation: physical pair p stored at column col(p).
  const int vcol = ((kp & 3) << 1) + ((kp >> 2) & 1) + (kp & ~7);

  f32x4 oacc[4];
#pragma unroll
  for (int c = 0; c < 4; ++c) oacc[c] = (f32x4){0.f, 0.f, 0.f, 0.f};
  float lsum = 0.f;                   // partial row-sum for query l16

  const int qi = qi_base + wv * 16 + l16;   // this lane's query row
  // bias0[r] = -sl2*(qi - kj) - 12*log2(e) at kj = kts2*64 + quad*4 + r
  float bias0[4];
#pragma unroll
  for (int r = 0; r < 4; ++r)
    bias0[r] = sl2 * (float)(kts2 * 64 + quad * 4 + r - qi) - 17.312340490667562f;

  // staged tile registers: loaded one tile EARLY, written to LDS in the
  // protected staging slot (between the two barriers).
  bf16x8 pka, pkb, pva, pvb;
  auto loadK = [&](int kt) {
    const short* g0 = K + base + (size_t)(kt * 64 + srow) * DM + scol;
    pka = *(const bf16x8*)g0;
    pkb = *(const bf16x8*)(g0 + 32 * DM);
  };
  auto loadV = [&](int kt) {
    const short* v0 = V + base + (size_t)(kt * 64 + 2 * kp) * DM + d0;
    pva = *(const bf16x8*)v0;
    pvb = *(const bf16x8*)(v0 + DM);
  };
  auto writeK = [&]() {
    *(bf16x8*)&sK[srow][scol]      = pka;
    *(bf16x8*)&sK[srow + 32][scol] = pkb;
  };
  auto packV = [&]() {
    const unsigned* au = (const unsigned*)&pva;
    const unsigned* bu = (const unsigned*)&pvb;
#pragma unroll
    for (int e = 0; e < 4; ++e) {
      // {lo16 = pva.short[2e] (key 2kp), hi16 = pvb.short[2e] (key 2kp+1)}
      sVt2[d0 + 2 * e][vcol]     = __builtin_amdgcn_perm(bu[e], au[e], 0x05040100u);
      sVt2[d0 + 2 * e + 1][vcol] = __builtin_amdgcn_perm(bu[e], au[e], 0x07060302u);
    }
  };

  auto tile = [&](int kt, auto mc) {
    constexpr bool MASK = decltype(mc)::value;
    const int k0 = kt * 64;
    __syncthreads();   // protect sK/sVt2 from previous tile's readers
    writeK();          // stage tile t (vmcnt wait: loads are one tile old)
    packV();
    if (kt + 1 < kte) {          // issue next tile's loads (regs)
      loadK(kt + 1);
      loadV(kt + 1);
    }
    __syncthreads();   // staged LDS visible to all waves

    // S^T = K Q^T : lane holds S[key=c*16+quad*4+r][q=l16]
    f32x4 sacc[4];
#pragma unroll
    for (int c = 0; c < 4; ++c) {
      f32x4 a = (f32x4){0.f, 0.f, 0.f, 0.f};
      a = __builtin_amdgcn_mfma_f32_16x16x32_bf16(
              *(const bf16x8*)&sK[c * 16 + l16][quad * 8], qf[0], a, 0, 0, 0);
      a = __builtin_amdgcn_mfma_f32_16x16x32_bf16(
              *(const bf16x8*)&sK[c * 16 + l16][32 + quad * 8], qf[1], a, 0, 0, 0);
      sacc[c] = a;
    }

    // softmax numerator in-lane: p = exp2(sacc*C1 + bias0[r] + bAdd[c])
    const float bAdd[4] = {0.f, bA1, bA2, bA3};
    float pv[4][4];
    int dq = 0;
    if constexpr (MASK) dq = qi - k0 - quad * 4;   // keep if c*16+r <= dq
#pragma unroll
    for (int c = 0; c < 4; ++c) {
#pragma unroll
      for (int r = 0; r < 4; ++r) {
        float p = EXP2F(fmaf(sacc[c][r], C1, bias0[r] + bAdd[c]));
        if constexpr (MASK) p = (c * 16 + r <= dq) ? p : 0.0f;
        pv[c][r] = p;
      }
      lsum += (pv[c][0] + pv[c][1]) + (pv[c][2] + pv[c][3]);
    }

    // O += P V : A-frag assembled in registers (2 swaps per 32-key half)
#pragma unroll
    for (int s = 0; s < 2; ++s) {
      unsigned X = cvt_pk_bf16(pv[2 * s][0],     pv[2 * s][1]);
      unsigned Y = cvt_pk_bf16(pv[2 * s][2],     pv[2 * s][3]);
      unsigned Z = cvt_pk_bf16(pv[2 * s + 1][0], pv[2 * s + 1][1]);
      unsigned W = cvt_pk_bf16(pv[2 * s + 1][2], pv[2 * s + 1][3]);
      permlane32_swap(X, Z);   // X=w0, Z=w1
      permlane32_swap(Y, W);   // Y=w2, W=w3
      bf16x8 pa;
      unsigned* pw = (unsigned*)&pa;
      pw[0] = X; pw[1] = Z; pw[2] = Y; pw[3] = W;
#pragma unroll
      for (int c = 0; c < 4; ++c) {
        const unsigned* vp = &sVt2[c * 16 + l16][s * 16 + quad * 4];
        bf16x4 vlo = *(const bf16x4*)vp;
        bf16x4 vhi = *(const bf16x4*)(vp + 2);
        bf16x8 vf = {vlo[0], vlo[1], vlo[2], vlo[3], vhi[0], vhi[1], vhi[2], vhi[3]};
        oacc[c] = __builtin_amdgcn_mfma_f32_16x16x32_bf16(pa, vf, oacc[c], 0, 0, 0);
      }
    }

#pragma unroll
    for (int r = 0; r < 4; ++r) bias0[r] += c64;   // k0 advances 64 next tile
  };

  if (kts2 < kte) {
    // prologue: issue first tile's loads (regs only; LDS writes in tile 0)
    loadK(kts2);
    loadV(kts2);
    // all tiles except the diagonal (last of the LAST chunk) are fully causal
    const int kfull = (kte == n) ? (kte - 1) : kte;
    for (int kt = kts2; kt < kfull; ++kt) tile(kt, BoolT<false>{});
    if (kte == n) tile(n - 1, BoolT<true>{});   // diagonal tile: mask
  }
  // else: fully-skipped chunk -> zero partials below

  // epilogue: unnormalized O partial (bf16) + l partial (fp32)
  {
    // total l for query l16: reduce over the 4 quad lanes
    float lt = lsum;
    lt += __shfl_xor(lt, 16);
    lt += __shfl_xor(lt, 32);
    const int pidx = (b * NH + h) * NCHB + item;
    short* po = Po + (size_t)pidx * 4096;   // [64 rows][64 dims]
    float* pl = Pl + (size_t)pidx * 64;
#pragma unroll
    for (int r = 0; r < 4; ++r) {
      const int row = wv * 16 + quad * 4 + r;
      const float lr = __shfl(lt, quad * 4 + r, 16);  // l of query quad*4+r
      if (l16 == 0) pl[row] = lr;
#pragma unroll
      for (int c = 0; c < 4; ++c)
        po[row * 64 + c * 16 + l16] = f2bf(oacc[c][r]);
    }
  }
}

// ---------------------------------------------------------------------------
// Combine: O[row] = (sum_j Oj)/(sum_j lj) -> bf16, for ALL query tiles.
// chunks per qt: (qt>>3)+1; slab base cum(qt) = (g+1)*(4g + (qt&7)), g=qt>>3.
// ---------------------------------------------------------------------------
__global__ __launch_bounds__(256) void combine(const short* __restrict__ Po,
                                               const float* __restrict__ Pl,
                                               short* __restrict__ O) {
  const int g = blockIdx.x * 32 + (threadIdx.x >> 3);   // 0..65535
  const int d = (threadIdx.x & 7) << 3;
  const int row = g & 63;
  const int qt  = (g >> 6) & 31;
  const int h   = (g >> 11) & 15;
  const int b   = g >> 15;
  const int gq  = qt >> 3;
  const int nch = gq + 1;
  const int cum = (gq + 1) * (4 * gq + (qt & 7));
  const int sbase = (b * NH + h) * NCHB + cum;

  float l = 0.f;
  float acc[8] = {0.f, 0.f, 0.f, 0.f, 0.f, 0.f, 0.f, 0.f};
  for (int jj = 0; jj < nch; ++jj) {
    l += Pl[(size_t)(sbase + jj) * 64 + row];
    const short* p = Po + (size_t)(sbase + jj) * 4096 + row * 64 + d;
    bf16x8 a = *(const bf16x8*)p;
#pragma unroll
    for (int e = 0; e < 8; ++e) acc[e] += bf2f(a[e]);
  }
  const float inv = 1.0f / fmaxf(l, 1e-37f);
  const int qi = qt * 64 + row;
  short* orow = O + (size_t)b * T_SEQ * DM + (size_t)qi * DM + h * HD + d;
  bf16x8 o;
#pragma unroll
  for (int e = 0; e < 8; ++e) o[e] = f2bf(acc[e] * inv);
  *(bf16x8*)orow = o;
}

// ---------------------------------------------------------------------------
extern "C" void kernel_launch(void* const* d_in, const int* in_sizes, int n_in,
                              void* d_out, int out_size, void* d_ws, size_t ws_size,
                              hipStream_t stream) {
  float* out = (float*)d_out;   // fp32 output

  short* ws = (short*)d_ws;
  const size_t plane = (size_t)NROW * DM;   // 4M elements
  const size_t wsz   = (size_t)DM * DM;     // 1M elements
  const size_t nslab = (size_t)32 * NCHB;   // 2560 partial slabs
  short* xb  = ws;
  short* Wqb = xb + plane;
  short* Wkb = Wqb + wsz;
  short* Wvb = Wkb + wsz;
  short* Wob = Wvb + wsz;
  short* Qb  = Wob + wsz;
  short* Kb  = Qb + plane;
  short* Vb  = Kb + plane;
  short* Ab  = Vb + plane;
  short* Po  = Ab + plane;                  // 2560 slabs * 4096 bf16 = 21 MB
  float* Pl  = (float*)(Po + nslab * 4096); // 2560 * 64 fp32 = 655 KB

  dim3 blk(256);
  convert_all<<<8192, blk, 0, stream>>>(
      (const float*)d_in[0], (const float*)d_in[1], (const float*)d_in[2],
      (const float*)d_in[3], (const float*)d_in[4],
      xb, Wqb, Wkb, Wvb, Wob);

  gemm_qkv<<<dim3(NROW / 128, DM / 128, 3), blk, 0, stream>>>(xb, Wqb, Wkb, Wvb, Qb, Kb, Vb);
  flash_alibi<<<dim3(NCHB, NH, 2), blk, 0, stream>>>(Qb, Kb, Vb, Ab, Po, Pl);
  combine<<<2048, blk, 0, stream>>>(Po, Pl, Ab);
  gemm_out<<<dim3(NROW / 64, DM / 128, 1), blk, 0, stream>>>(Ab, Wob, out);
}

// Round 13
// 165.946 us; speedup vs baseline: 1.8902x; 1.0173x over previous
//
#include <hip/hip_runtime.h>
#include <math.h>

// ALiBi attention: B=2, T=2048, D=1024, H=16, hd=64. fp32 in/out.
// Round 20: port the VERIFIED round-12 flash staging pattern (T14 early
// issue / write-late: loads for iter t+1 issued right after iter t's
// ds_writes; writes sit between the two barriers so the vmcnt wait is a
// full compute-phase old) to BOTH GEMMs. Reg-staged ds_write_b128 at the
// same linear base+lane*16B addresses the DMA used (conflict-free).
// MFMA schedule / LDS layout / sync structure unchanged.
// Flash (round-18/19 verified) / convert / combine byte-identical.

#define T_SEQ 2048
#define DM    1024
#define NH    16
#define HD    64
#define NROW  4096   // B*T
#define NCHB  80     // chunks per (h,b): qt/8 -> 1,2,3,4 chunks

typedef __attribute__((ext_vector_type(8))) short bf16x8;
typedef __attribute__((ext_vector_type(4))) short bf16x4;
typedef __attribute__((ext_vector_type(4))) float f32x4;

template <bool M> struct BoolT { static constexpr bool value = M; };

__device__ __forceinline__ short f2bf(float f) {
  unsigned u = __float_as_uint(f);
  u += 0x7FFFu + ((u >> 16) & 1u);
  return (short)(u >> 16);
}
__device__ __forceinline__ float bf2f(short s) {
  return __uint_as_float(((unsigned)(unsigned short)s) << 16);
}

// RNE pack of two f32 -> {lo16=bf16(a), hi16=bf16(b)} in one instruction.
__device__ __forceinline__ unsigned cvt_pk_bf16(float a, float b) {
  unsigned r;
  asm("v_cvt_pk_bf16_f32 %0, %1, %2" : "=v"(r) : "v"(a), "v"(b));
  return r;
}

// v_permlane32_swap_b32 a, b: a.hi32lanes <-> b.lo32lanes.
__device__ __forceinline__ void permlane32_swap(unsigned &a, unsigned &b) {
  asm("v_permlane32_swap_b32 %0, %1" : "+v"(a), "+v"(b));
}

#if __has_builtin(__builtin_amdgcn_exp2f)
#define EXP2F(x) __builtin_amdgcn_exp2f(x)
#else
#define EXP2F(x) exp2f(x)
#endif

// ---------------------------------------------------------------------------
// Merged fp32->bf16 conversion: x (4M) + 4 weights (1M each), 2M float4 groups.
// ---------------------------------------------------------------------------
__global__ __launch_bounds__(256) void convert_all(
    const float* __restrict__ x,  const float* __restrict__ wq,
    const float* __restrict__ wk, const float* __restrict__ wv,
    const float* __restrict__ wo,
    short* __restrict__ xb,  short* __restrict__ wqb, short* __restrict__ wkb,
    short* __restrict__ wvb, short* __restrict__ wob) {
  const int i = blockIdx.x * 256 + threadIdx.x;
  const float* s; short* d; int off;
  if (i < (1 << 20)) { s = x; d = xb; off = i; }
  else {
    const int j = i - (1 << 20);
    const int w = j >> 18;
    off = j & ((1 << 18) - 1);
    s = (w == 0) ? wq : (w == 1) ? wk : (w == 2) ? wv : wo;
    d = (w == 0) ? wqb : (w == 1) ? wkb : (w == 2) ? wvb : wob;
  }
  const float4 v = ((const float4*)s)[off];
  bf16x4 o = {f2bf(v.x), f2bf(v.y), f2bf(v.z), f2bf(v.w)};
  *(bf16x4*)(d + 4 * (size_t)off) = o;
}

// ---------------------------------------------------------------------------
// GEMM 128x128, BK=64, early-issue reg staging (flash round-12 pattern):
//   barrier1 -> ds_write regs (loaded one iter ago) -> issue loads(k0+64)
//   -> barrier2 -> 32 MFMAs.
// LDS: two verified [128][32] half-buffers per operand (64B row stride).
// Reg-staged writes land at base + lane*16B (linear, conflict-free).
// ---------------------------------------------------------------------------
template <typename OutT>
__device__ __forceinline__ void gemm_bk64_body(const short* __restrict__ A,
                                               const short* __restrict__ W,
                                               OutT* __restrict__ C) {
  __shared__ short sA0[128][32];
  __shared__ short sA1[128][32];
  __shared__ short sB0[128][32];
  __shared__ short sB1[128][32];
  const int tid  = threadIdx.x;
  const int lane = tid & 63, wv = tid >> 6;
  const int quad = lane >> 4, l16 = lane & 15;
  const int wm = (wv >> 1) * 64, wn = (wv & 1) * 64;
  const size_t m0 = (size_t)blockIdx.x * 128, n0 = (size_t)blockIdx.y * 128;

  f32x4 acc[4][4];
#pragma unroll
  for (int i = 0; i < 4; ++i)
#pragma unroll
    for (int j = 0; j < 4; ++j) acc[i][j] = (f32x4){0.f, 0.f, 0.f, 0.f};

  const int grow = lane >> 2;          // 0..15
  const int gcol = (lane & 3) << 3;    // 0..24 shorts (within 32-col half)

  bf16x8 ra[4], rb[4];                 // staged tile regs (one iter early)
  auto loadT = [&](int k0) {
    const short* ga = A + (m0 + wv * 32 + grow) * DM + k0 + gcol;
    ra[0] = *(const bf16x8*)ga;
    ra[1] = *(const bf16x8*)(ga + 16 * DM);
    ra[2] = *(const bf16x8*)(ga + 32);
    ra[3] = *(const bf16x8*)(ga + 16 * DM + 32);
    const short* gb = W + (n0 + wv * 32 + grow) * DM + k0 + gcol;
    rb[0] = *(const bf16x8*)gb;
    rb[1] = *(const bf16x8*)(gb + 16 * DM);
    rb[2] = *(const bf16x8*)(gb + 32);
    rb[3] = *(const bf16x8*)(gb + 16 * DM + 32);
  };
  auto writeT = [&]() {
    *(bf16x8*)&sA0[wv * 32 + grow][gcol]      = ra[0];
    *(bf16x8*)&sA0[wv * 32 + 16 + grow][gcol] = ra[1];
    *(bf16x8*)&sA1[wv * 32 + grow][gcol]      = ra[2];
    *(bf16x8*)&sA1[wv * 32 + 16 + grow][gcol] = ra[3];
    *(bf16x8*)&sB0[wv * 32 + grow][gcol]      = rb[0];
    *(bf16x8*)&sB0[wv * 32 + 16 + grow][gcol] = rb[1];
    *(bf16x8*)&sB1[wv * 32 + grow][gcol]      = rb[2];
    *(bf16x8*)&sB1[wv * 32 + 16 + grow][gcol] = rb[3];
  };

  loadT(0);   // prologue: issue first tile's loads (regs only)

  for (int k0 = 0; k0 < DM; k0 += 64) {
    __syncthreads();                 // LDS free (prev iter's readers done)
    writeT();                        // vmcnt wait here: loads one iter old
    if (k0 + 64 < DM) loadT(k0 + 64);
    __syncthreads();                 // staged LDS visible

    {
      bf16x8 af[4], bfr[4];
#pragma unroll
      for (int t = 0; t < 4; ++t) {
        af[t]  = *(const bf16x8*)&sA0[wm + t * 16 + l16][quad * 8];
        bfr[t] = *(const bf16x8*)&sB0[wn + t * 16 + l16][quad * 8];
      }
#pragma unroll
      for (int mt = 0; mt < 4; ++mt)
#pragma unroll
        for (int nt = 0; nt < 4; ++nt)
          acc[mt][nt] = __builtin_amdgcn_mfma_f32_16x16x32_bf16(af[mt], bfr[nt], acc[mt][nt], 0, 0, 0);
    }
    {
      bf16x8 af[4], bfr[4];
#pragma unroll
      for (int t = 0; t < 4; ++t) {
        af[t]  = *(const bf16x8*)&sA1[wm + t * 16 + l16][quad * 8];
        bfr[t] = *(const bf16x8*)&sB1[wn + t * 16 + l16][quad * 8];
      }
#pragma unroll
      for (int mt = 0; mt < 4; ++mt)
#pragma unroll
        for (int nt = 0; nt < 4; ++nt)
          acc[mt][nt] = __builtin_amdgcn_mfma_f32_16x16x32_bf16(af[mt], bfr[nt], acc[mt][nt], 0, 0, 0);
    }
  }
#pragma unroll
  for (int mt = 0; mt < 4; ++mt) {
#pragma unroll
    for (int r = 0; r < 4; ++r) {
      const size_t m = m0 + wm + mt * 16 + quad * 4 + r;
      OutT* crow = C + m * DM;
#pragma unroll
      for (int nt = 0; nt < 4; ++nt) {
        const float v = acc[mt][nt][r];
        if constexpr (sizeof(OutT) == 2)
          crow[n0 + wn + nt * 16 + l16] = f2bf(v);
        else
          crow[n0 + wn + nt * 16 + l16] = v;
      }
    }
  }
}

__global__ __launch_bounds__(256) void gemm_qkv(
    const short* __restrict__ x,
    const short* __restrict__ Wq, const short* __restrict__ Wk, const short* __restrict__ Wv,
    short* __restrict__ Qb, short* __restrict__ Kb, short* __restrict__ Vb) {
  const short* W = (blockIdx.z == 0) ? Wq : (blockIdx.z == 1) ? Wk : Wv;
  short*       C = (blockIdx.z == 0) ? Qb : (blockIdx.z == 1) ? Kb : Vb;
  gemm_bk64_body<short>(x, W, C);
}

// ---------------------------------------------------------------------------
// Output GEMM: 64x128 tile, early-issue reg staging (same pattern).
// Staging: 12 chunks of 16 rows ([A:4][B:8]), 3 chunks per wave, 3 regs.
// ---------------------------------------------------------------------------
__global__ __launch_bounds__(256) void gemm_out(const short* __restrict__ A,
                                                const short* __restrict__ W,
                                                float* __restrict__ C) {
  __shared__ short sA[64][32];
  __shared__ short sB[128][32];
  const int tid  = threadIdx.x;
  const int lane = tid & 63, wv = tid >> 6;
  const int quad = lane >> 4, l16 = lane & 15;
  const int wm = (wv >> 1) * 32, wn = (wv & 1) * 64;
  const size_t m0 = (size_t)blockIdx.x * 64, n0 = (size_t)blockIdx.y * 128;

  f32x4 acc[2][4];
#pragma unroll
  for (int i = 0; i < 2; ++i)
#pragma unroll
    for (int j = 0; j < 4; ++j) acc[i][j] = (f32x4){0.f, 0.f, 0.f, 0.f};

  const int grow = lane >> 2;
  const int gcol = (lane & 3) << 3;

  bf16x8 rg[3];
  auto loadT = [&](int k0) {
#pragma unroll
    for (int cc = 0; cc < 3; ++cc) {
      const int i = wv * 3 + cc;   // 0..11, wave-uniform per call
      const short* src = (i < 4)
          ? A + (m0 + i * 16 + grow) * DM + k0 + gcol
          : W + (n0 + (i - 4) * 16 + grow) * DM + k0 + gcol;
      rg[cc] = *(const bf16x8*)src;
    }
  };
  auto writeT = [&]() {
#pragma unroll
    for (int cc = 0; cc < 3; ++cc) {
      const int i = wv * 3 + cc;
      short* dst = (i < 4) ? &sA[i * 16 + grow][gcol]
                           : &sB[(i - 4) * 16 + grow][gcol];
      *(bf16x8*)dst = rg[cc];
    }
  };

  loadT(0);

  for (int k0 = 0; k0 < DM; k0 += 32) {
    __syncthreads();
    writeT();
    if (k0 + 32 < DM) loadT(k0 + 32);
    __syncthreads();

    bf16x8 af[2], bfr[4];
#pragma unroll
    for (int t = 0; t < 2; ++t)
      af[t] = *(const bf16x8*)&sA[wm + t * 16 + l16][quad * 8];
#pragma unroll
    for (int t = 0; t < 4; ++t)
      bfr[t] = *(const bf16x8*)&sB[wn + t * 16 + l16][quad * 8];
#pragma unroll
    for (int mt = 0; mt < 2; ++mt)
#pragma unroll
      for (int nt = 0; nt < 4; ++nt)
        acc[mt][nt] = __builtin_amdgcn_mfma_f32_16x16x32_bf16(af[mt], bfr[nt], acc[mt][nt], 0, 0, 0);
  }
#pragma unroll
  for (int mt = 0; mt < 2; ++mt) {
#pragma unroll
    for (int r = 0; r < 4; ++r) {
      const size_t m = m0 + wm + mt * 16 + quad * 4 + r;
      float* crow = C + m * DM;
#pragma unroll
      for (int nt = 0; nt < 4; ++nt)
        crow[n0 + wn + nt * 16 + l16] = acc[mt][nt][r];
    }
  }
}

// ---------------------------------------------------------------------------
// Flash attention, ALiBi, causal — uniform-chunk mapping, swapped QK^T,
// ALiBi distance skip (round-18 verified, byte-identical).
// ---------------------------------------------------------------------------
__global__ __launch_bounds__(256) void flash_alibi(const short* __restrict__ Q,
                                                   const short* __restrict__ K,
                                                   const short* __restrict__ V,
                                                   short* __restrict__ O,
                                                   short* __restrict__ Po,
                                                   float* __restrict__ Pl) {
  __shared__ short sK[64][72];             // [key][dim], padded
  __shared__ unsigned int sVt2[64][34];    // [dim][keypair-permuted]

  const int tid  = threadIdx.x;
  const int lane = tid & 63, wv = tid >> 6;
  const int quad = lane >> 4, l16 = lane & 15;
  const int item = blockIdx.x;

  int qt, j;
  if (item < 8)       { qt = item;                j = 0; }
  else if (item < 24) { qt = 8 + (item - 8) / 2;  j = (item - 8) % 2; }
  else if (item < 48) { qt = 16 + (item - 24) / 3; j = (item - 24) % 3; }
  else                { qt = 24 + (item - 48) / 4; j = (item - 48) % 4; }

  const int n   = qt + 1;
  const int kts = j * 8;
  const int kte = (kts + 8 < n) ? (kts + 8) : n;

  const int h = blockIdx.y, b = blockIdx.z;
  const size_t base = (size_t)b * T_SEQ * DM + (size_t)h * HD;
  const int qi_base = qt * 64;

  // Q fragments (identical layout serves as B-operand: col=l16, k=quad*8+j)
  bf16x8 qf[2];
  {
    const int qrow = qi_base + wv * 16 + l16;
    const short* qp = Q + base + (size_t)qrow * DM + quad * 8;
    qf[0] = *(const bf16x8*)(qp);
    qf[1] = *(const bf16x8*)(qp + 32);
  }

  const float slope = exp2f(-0.5f * (float)(h + 1));
  const float sl2   = slope * 1.4426950408889634f;     // slope * log2(e)
  const float C1    = 0.18033688011112042f;            // 0.125 * log2(e)
  const float bA1 = 16.f * sl2, bA2 = 32.f * sl2, bA3 = 48.f * sl2;
  const float c64 = 64.f * sl2;

  // ALiBi skip: keep tile iff qt-kt <= D, D = floor((40/sl2 + 63)/64).
  const int D = (int)((40.0f / sl2 + 63.0f) * 0.015625f);
  const int kmin = qt - D;
  const int kts2 = (kts > kmin) ? kts : kmin;

  const int srow = tid >> 3;          // K staging row (0..31)
  const int scol = (tid & 7) << 3;    // K staging col
  const int kp   = tid >> 3;          // V staging key pair (0..31)
  const int d0   = (tid & 7) << 3;    // V staging dim group
  // PV key-order permutation: physical pair p stored at column col(p).
  const int vcol = ((kp & 3) << 1) + ((kp >> 2) & 1) + (kp & ~7);

  f32x4 oacc[4];
#pragma unroll
  for (int c = 0; c < 4; ++c) oacc[c] = (f32x4){0.f, 0.f, 0.f, 0.f};
  float lsum = 0.f;                   // partial row-sum for query l16

  const int qi = qi_base + wv * 16 + l16;   // this lane's query row
  // bias0[r] = -sl2*(qi - kj) - 12*log2(e) at kj = kts2*64 + quad*4 + r
  float bias0[4];
#pragma unroll
  for (int r = 0; r < 4; ++r)
    bias0[r] = sl2 * (float)(kts2 * 64 + quad * 4 + r - qi) - 17.312340490667562f;

  // staged tile registers: loaded one tile EARLY, written to LDS in the
  // protected staging slot (between the two barriers).
  bf16x8 pka, pkb, pva, pvb;
  auto loadK = [&](int kt) {
    const short* g0 = K + base + (size_t)(kt * 64 + srow) * DM + scol;
    pka = *(const bf16x8*)g0;
    pkb = *(const bf16x8*)(g0 + 32 * DM);
  };
  auto loadV = [&](int kt) {
    const short* v0 = V + base + (size_t)(kt * 64 + 2 * kp) * DM + d0;
    pva = *(const bf16x8*)v0;
    pvb = *(const bf16x8*)(v0 + DM);
  };
  auto writeK = [&]() {
    *(bf16x8*)&sK[srow][scol]      = pka;
    *(bf16x8*)&sK[srow + 32][scol] = pkb;
  };
  auto packV = [&]() {
    const unsigned* au = (const unsigned*)&pva;
    const unsigned* bu = (const unsigned*)&pvb;
#pragma unroll
    for (int e = 0; e < 4; ++e) {
      // {lo16 = pva.short[2e] (key 2kp), hi16 = pvb.short[2e] (key 2kp+1)}
      sVt2[d0 + 2 * e][vcol]     = __builtin_amdgcn_perm(bu[e], au[e], 0x05040100u);
      sVt2[d0 + 2 * e + 1][vcol] = __builtin_amdgcn_perm(bu[e], au[e], 0x07060302u);
    }
  };

  auto tile = [&](int kt, auto mc) {
    constexpr bool MASK = decltype(mc)::value;
    const int k0 = kt * 64;
    __syncthreads();   // protect sK/sVt2 from previous tile's readers
    writeK();          // stage tile t (vmcnt wait: loads are one tile old)
    packV();
    if (kt + 1 < kte) {          // issue next tile's loads (regs)
      loadK(kt + 1);
      loadV(kt + 1);
    }
    __syncthreads();   // staged LDS visible to all waves

    // S^T = K Q^T : lane holds S[key=c*16+quad*4+r][q=l16]
    f32x4 sacc[4];
#pragma unroll
    for (int c = 0; c < 4; ++c) {
      f32x4 a = (f32x4){0.f, 0.f, 0.f, 0.f};
      a = __builtin_amdgcn_mfma_f32_16x16x32_bf16(
              *(const bf16x8*)&sK[c * 16 + l16][quad * 8], qf[0], a, 0, 0, 0);
      a = __builtin_amdgcn_mfma_f32_16x16x32_bf16(
              *(const bf16x8*)&sK[c * 16 + l16][32 + quad * 8], qf[1], a, 0, 0, 0);
      sacc[c] = a;
    }

    // softmax numerator in-lane: p = exp2(sacc*C1 + bias0[r] + bAdd[c])
    const float bAdd[4] = {0.f, bA1, bA2, bA3};
    float pv[4][4];
    int dq = 0;
    if constexpr (MASK) dq = qi - k0 - quad * 4;   // keep if c*16+r <= dq
#pragma unroll
    for (int c = 0; c < 4; ++c) {
#pragma unroll
      for (int r = 0; r < 4; ++r) {
        float p = EXP2F(fmaf(sacc[c][r], C1, bias0[r] + bAdd[c]));
        if constexpr (MASK) p = (c * 16 + r <= dq) ? p : 0.0f;
        pv[c][r] = p;
      }
      lsum += (pv[c][0] + pv[c][1]) + (pv[c][2] + pv[c][3]);
    }

    // O += P V : A-frag assembled in registers (2 swaps per 32-key half)
#pragma unroll
    for (int s = 0; s < 2; ++s) {
      unsigned X = cvt_pk_bf16(pv[2 * s][0],     pv[2 * s][1]);
      unsigned Y = cvt_pk_bf16(pv[2 * s][2],     pv[2 * s][3]);
      unsigned Z = cvt_pk_bf16(pv[2 * s + 1][0], pv[2 * s + 1][1]);
      unsigned W = cvt_pk_bf16(pv[2 * s + 1][2], pv[2 * s + 1][3]);
      permlane32_swap(X, Z);   // X=w0, Z=w1
      permlane32_swap(Y, W);   // Y=w2, W=w3
      bf16x8 pa;
      unsigned* pw = (unsigned*)&pa;
      pw[0] = X; pw[1] = Z; pw[2] = Y; pw[3] = W;
#pragma unroll
      for (int c = 0; c < 4; ++c) {
        const unsigned* vp = &sVt2[c * 16 + l16][s * 16 + quad * 4];
        bf16x4 vlo = *(const bf16x4*)vp;
        bf16x4 vhi = *(const bf16x4*)(vp + 2);
        bf16x8 vf = {vlo[0], vlo[1], vlo[2], vlo[3], vhi[0], vhi[1], vhi[2], vhi[3]};
        oacc[c] = __builtin_amdgcn_mfma_f32_16x16x32_bf16(pa, vf, oacc[c], 0, 0, 0);
      }
    }

#pragma unroll
    for (int r = 0; r < 4; ++r) bias0[r] += c64;   // k0 advances 64 next tile
  };

  if (kts2 < kte) {
    // prologue: issue first tile's loads (regs only; LDS writes in tile 0)
    loadK(kts2);
    loadV(kts2);
    // all tiles except the diagonal (last of the LAST chunk) are fully causal
    const int kfull = (kte == n) ? (kte - 1) : kte;
    for (int kt = kts2; kt < kfull; ++kt) tile(kt, BoolT<false>{});
    if (kte == n) tile(n - 1, BoolT<true>{});   // diagonal tile: mask
  }
  // else: fully-skipped chunk -> zero partials below

  // epilogue: unnormalized O partial (bf16) + l partial (fp32)
  {
    // total l for query l16: reduce over the 4 quad lanes
    float lt = lsum;
    lt += __shfl_xor(lt, 16);
    lt += __shfl_xor(lt, 32);
    const int pidx = (b * NH + h) * NCHB + item;
    short* po = Po + (size_t)pidx * 4096;   // [64 rows][64 dims]
    float* pl = Pl + (size_t)pidx * 64;
#pragma unroll
    for (int r = 0; r < 4; ++r) {
      const int row = wv * 16 + quad * 4 + r;
      const float lr = __shfl(lt, quad * 4 + r, 16);  // l of query quad*4+r
      if (l16 == 0) pl[row] = lr;
#pragma unroll
      for (int c = 0; c < 4; ++c)
        po[row * 64 + c * 16 + l16] = f2bf(oacc[c][r]);
    }
  }
}

// ---------------------------------------------------------------------------
// Combine: O[row] = (sum_j Oj)/(sum_j lj) -> bf16, for ALL query tiles.
// chunks per qt: (qt>>3)+1; slab base cum(qt) = (g+1)*(4g + (qt&7)), g=qt>>3.
// ---------------------------------------------------------------------------
__global__ __launch_bounds__(256) void combine(const short* __restrict__ Po,
                                               const float* __restrict__ Pl,
                                               short* __restrict__ O) {
  const int g = blockIdx.x * 32 + (threadIdx.x >> 3);   // 0..65535
  const int d = (threadIdx.x & 7) << 3;
  const int row = g & 63;
  const int qt  = (g >> 6) & 31;
  const int h   = (g >> 11) & 15;
  const int b   = g >> 15;
  const int gq  = qt >> 3;
  const int nch = gq + 1;
  const int cum = (gq + 1) * (4 * gq + (qt & 7));
  const int sbase = (b * NH + h) * NCHB + cum;

  float l = 0.f;
  float acc[8] = {0.f, 0.f, 0.f, 0.f, 0.f, 0.f, 0.f, 0.f};
  for (int jj = 0; jj < nch; ++jj) {
    l += Pl[(size_t)(sbase + jj) * 64 + row];
    const short* p = Po + (size_t)(sbase + jj) * 4096 + row * 64 + d;
    bf16x8 a = *(const bf16x8*)p;
#pragma unroll
    for (int e = 0; e < 8; ++e) acc[e] += bf2f(a[e]);
  }
  const float inv = 1.0f / fmaxf(l, 1e-37f);
  const int qi = qt * 64 + row;
  short* orow = O + (size_t)b * T_SEQ * DM + (size_t)qi * DM + h * HD + d;
  bf16x8 o;
#pragma unroll
  for (int e = 0; e < 8; ++e) o[e] = f2bf(acc[e] * inv);
  *(bf16x8*)orow = o;
}

// ---------------------------------------------------------------------------
extern "C" void kernel_launch(void* const* d_in, const int* in_sizes, int n_in,
                              void* d_out, int out_size, void* d_ws, size_t ws_size,
                              hipStream_t stream) {
  float* out = (float*)d_out;   // fp32 output

  short* ws = (short*)d_ws;
  const size_t plane = (size_t)NROW * DM;   // 4M elements
  const size_t wsz   = (size_t)DM * DM;     // 1M elements
  const size_t nslab = (size_t)32 * NCHB;   // 2560 partial slabs
  short* xb  = ws;
  short* Wqb = xb + plane;
  short* Wkb = Wqb + wsz;
  short* Wvb = Wkb + wsz;
  short* Wob = Wvb + wsz;
  short* Qb  = Wob + wsz;
  short* Kb  = Qb + plane;
  short* Vb  = Kb + plane;
  short* Ab  = Vb + plane;
  short* Po  = Ab + plane;                  // 2560 slabs * 4096 bf16 = 21 MB
  float* Pl  = (float*)(Po + nslab * 4096); // 2560 * 64 fp32 = 655 KB

  dim3 blk(256);
  convert_all<<<8192, blk, 0, stream>>>(
      (const float*)d_in[0], (const float*)d_in[1], (const float*)d_in[2],
      (const float*)d_in[3], (const float*)d_in[4],
      xb, Wqb, Wkb, Wvb, Wob);

  gemm_qkv<<<dim3(NROW / 128, DM / 128, 3), blk, 0, stream>>>(xb, Wqb, Wkb, Wvb, Qb, Kb, Vb);
  flash_alibi<<<dim3(NCHB, NH, 2), blk, 0, stream>>>(Qb, Kb, Vb, Ab, Po, Pl);
  combine<<<2048, blk, 0, stream>>>(Po, Pl, Ab);
  gemm_out<<<dim3(NROW / 64, DM / 128, 1), blk, 0, stream>>>(Ab, Wob, out);
}